// Round 4
// baseline (900.983 us; speedup 1.0000x reference)
//
#include <hip/hip_runtime.h>
#include <stdint.h>
#include <math.h>

// ---------------- problem constants ----------------
#define N_ROWS   16384
#define N_CODES  8192
#define DIMV     256
#define RT       32
#define CK       32
#define NCHUNK   (N_CODES / CK)
#define OUT_ZQ_N ((size_t)N_ROWS * DIMV)
#define OUT_LOSS OUT_ZQ_N
#define OUT_CODE (OUT_ZQ_N + 1)

// ---------------- workspace layout ----------------
#define WS_CBHI 0u
#define WS_CBLO 4194304u
#define WS_CBT  8388608u
#define WS_ACC  12582912u
#define WS_NEED (12582912u + 64u)

// ---------------- LDS layout (bytes) ----------------
// CB1: 16 blocks of 1024B (2 codes x 512B) at stride 1040 (=65*16) ->
//   GEMM1 read groups (kc>>1 + quad) mod 8 uniform => conflict-free.
// CBT: stride 1024 (block idx is wave-uniform => conflict-free), x2 buffers.
#define CB1H_OFF  0
#define CB1L_OFF  16640
#define CB1_BS    1040
#define CBT0_OFF  33280
#define CBT1_OFF  49664
#define P_OFF     66048    // [32 rows][40 ushort] hi; lo at +2560
#define P_SPLIT   2560
#define P_ROW     80
#define S2B_OFF   71168    // [2][32] f32
#define SKL_OFF   71424
#define TKL_OFF   71680
#define V1B_OFF   71936
#define I1B_OFF   72192
#define V2B_OFF   72448
#define I2B_OFF   72704
#define SMEM_BYTES 72960
#define ZT_ROWF   260      // z fp32 tile stride (floats), overlays 0..33280

typedef __attribute__((ext_vector_type(8))) short short8;
typedef __attribute__((ext_vector_type(4))) float float4v;

typedef __attribute__((address_space(1))) uint32_t g_u32;
typedef __attribute__((address_space(3))) uint32_t l_u32;

// async global->LDS DMA, 16B/lane; LDS dest = wave-uniform base + lane*16
__device__ __forceinline__ void dma16(const void* gsrc, void* ldst) {
  __builtin_amdgcn_global_load_lds((g_u32*)gsrc, (l_u32*)ldst, 16, 0, 0);
}

__device__ __forceinline__ uint32_t rotl32(uint32_t x, int r) {
  return __builtin_rotateleft32(x, (uint32_t)r);   // v_alignbit_b32
}

// Threefry-2x32, key=(0,42), counter=(0, c); out0^out1 (JAX partitionable).
__device__ __forceinline__ uint32_t threefry_bits(uint32_t c) {
  const uint32_t k0 = 0u, k1 = 42u;
  const uint32_t k2 = 0x1BD11BDAu ^ k0 ^ k1;
  uint32_t x0 = 0u + k0;
  uint32_t x1 = c + k1;
#define TF_R(r) { x0 += x1; x1 = rotl32(x1, r); x1 ^= x0; }
  TF_R(13) TF_R(15) TF_R(26) TF_R(6)
  x0 += k1; x1 += k2 + 1u;
  TF_R(17) TF_R(29) TF_R(16) TF_R(24)
  x0 += k2; x1 += k0 + 2u;
  TF_R(13) TF_R(15) TF_R(26) TF_R(6)
  x0 += k0; x1 += k1 + 3u;
  TF_R(17) TF_R(29) TF_R(16) TF_R(24)
  x0 += k1; x1 += k2 + 4u;
  TF_R(13) TF_R(15) TF_R(26) TF_R(6)
  x0 += k2; x1 += k0 + 5u;
#undef TF_R
  return x0 ^ x1;
}

// accurate gumbel for the v1 fallback path
__device__ __forceinline__ float gumbel_at_v1(uint32_t idx) {
  uint32_t bits = threefry_bits(idx);
  float u = __uint_as_float((bits >> 9) | 0x3f800000u) - 1.0f;
  u = fmaxf(u, 1.17549435e-38f);
  return -logf(-logf(u));
}

__device__ __forceinline__ unsigned short f2bf(float x) {
  uint32_t u = __float_as_uint(x);
  u += 0x7fffu + ((u >> 16) & 1u);
  return (unsigned short)(u >> 16);
}
__device__ __forceinline__ float bf2f(unsigned short h) {
  return __uint_as_float(((uint32_t)h) << 16);
}

// ================= prep: cb fp32 -> bf16 hi/lo + chunk-blocked transpose =================
__global__ __launch_bounds__(256)
void vq_prep(const float* __restrict__ cb, char* __restrict__ ws) {
  __shared__ unsigned short lhs[32 * 260];
  const int c = blockIdx.x;
  const int tid = threadIdx.x;
  const int k0 = c * 32;
  unsigned short* cbhi = (unsigned short*)(ws + WS_CBHI);
  unsigned short* cblo = (unsigned short*)(ws + WS_CBLO);
  unsigned short* cbt  = (unsigned short*)(ws + WS_CBT);
#pragma unroll
  for (int i = 0; i < 8; ++i) {
    int F = tid + i * 256;
    int code = F >> 6, d4 = (F & 63) * 4;
    float4 v = *(const float4*)(cb + (size_t)(k0 + code) * DIMV + d4);
    unsigned short h0 = f2bf(v.x), h1 = f2bf(v.y), h2 = f2bf(v.z), h3 = f2bf(v.w);
    unsigned short l0 = f2bf(v.x - bf2f(h0)), l1 = f2bf(v.y - bf2f(h1));
    unsigned short l2 = f2bf(v.z - bf2f(h2)), l3 = f2bf(v.w - bf2f(h3));
    ushort4 hv = {h0, h1, h2, h3};
    ushort4 lv = {l0, l1, l2, l3};
    *(ushort4*)(cbhi + (size_t)(k0 + code) * DIMV + d4) = hv;
    *(ushort4*)(cblo + (size_t)(k0 + code) * DIMV + d4) = lv;
    *(ushort4*)(&lhs[code * 260 + d4]) = hv;
  }
  __syncthreads();
  const int d = tid;
  unsigned short vals[32];
#pragma unroll
  for (int cc = 0; cc < 32; ++cc) vals[cc] = lhs[cc * 260 + d];
  unsigned short* base = cbt + (size_t)c * 8192 + (size_t)d * 32;
#pragma unroll
  for (int j = 0; j < 8; ++j) {
    ushort4 w = {vals[4 * j], vals[4 * j + 1], vals[4 * j + 2], vals[4 * j + 3]};
    *(ushort4*)(base + j * 4) = w;
  }
}

// ================= main v4: software-pipelined MFMA split-bf16 =================
__global__ __launch_bounds__(256, 2)
void vq_main_v2(const float* __restrict__ z, const float* __restrict__ cb,
                float* __restrict__ out, char* __restrict__ ws) {
  __shared__ __align__(16) char sm[SMEM_BYTES];
  const int tid  = threadIdx.x;
  const int wave = tid >> 6;
  const int lane = tid & 63;
  const int quad = lane >> 4;
  const int n    = lane & 15;
  const int mt   = wave & 1;
  const int nt   = wave >> 1;
  const int r0   = blockIdx.x * RT;
  const int myrow = mt * 16 + quad * 4;      // C-layout base row
  const char* cbhi_b = ws + WS_CBHI;
  const char* cblo_b = ws + WS_CBLO;
  const char* cbt_b  = ws + WS_CBT;
  float* wsA = (float*)(ws + WS_ACC);

  // ---- prologue: stage z fp32 tile, build A-fragments in registers ----
  {
    float* zts = (float*)sm;
#pragma unroll
    for (int i = 0; i < 8; ++i) {
      int F = tid + i * 256;
      int row = F >> 6, d4 = (F & 63) * 4;
      *(float4*)(zts + row * ZT_ROWF + d4) =
          *(const float4*)(z + (size_t)(r0 + row) * DIMV + d4);
    }
  }
  __syncthreads();
  short8 zhi[8], zlo[8];
  {
    const float* zts = (const float*)sm;
    const int rowl = mt * 16 + n;            // A-frag m = lane&15
#pragma unroll
    for (int ks = 0; ks < 8; ++ks) {
      const float* zp = zts + rowl * ZT_ROWF + ks * 32 + quad * 8;
      float4 f0 = *(const float4*)zp;
      float4 f1 = *(const float4*)(zp + 4);
      float ff0[4] = {f0.x, f0.y, f0.z, f0.w};
      float ff1[4] = {f1.x, f1.y, f1.z, f1.w};
#pragma unroll
      for (int j = 0; j < 4; ++j) {
        unsigned short h = f2bf(ff0[j]);
        zhi[ks][j] = (short)h;
        zlo[ks][j] = (short)f2bf(ff0[j] - bf2f(h));
      }
#pragma unroll
      for (int j = 0; j < 4; ++j) {
        unsigned short h = f2bf(ff1[j]);
        zhi[ks][4 + j] = (short)h;
        zlo[ks][4 + j] = (short)f2bf(ff1[j] - bf2f(h));
      }
    }
  }
  __syncthreads();   // all waves done reading z-tile (CB1 region reuse)

  // ---- prologue staging: CB1(0) + CBT(0) -> buf0 ----
#pragma unroll
  for (int i = 0; i < 4; ++i) {
    int b = wave * 4 + i;
    dma16(cbhi_b + (size_t)(2 * b) * 512 + (size_t)lane * 16, sm + CB1H_OFF + b * CB1_BS);
    dma16(cblo_b + (size_t)(2 * b) * 512 + (size_t)lane * 16, sm + CB1L_OFF + b * CB1_BS);
    dma16(cbt_b + (size_t)b * 1024 + (size_t)lane * 16, sm + CBT0_OFF + b * 1024);
  }
  __syncthreads();   // drain prologue DMA

  // ---- per-lane persistent state ----
  float skl[4] = {0.f, 0.f, 0.f, 0.f};
  float tkl[4] = {0.f, 0.f, 0.f, 0.f};
  float s2l[4] = {0.f, 0.f, 0.f, 0.f};
  float v1[4], v2[4];
  int   i1[4], i2[4];
  uint32_t idxr[4];
#pragma unroll
  for (int r = 0; r < 4; ++r) {
    v1[r] = -INFINITY; v2[r] = -INFINITY;
    i1[r] = 0x7fffffff; i2[r] = 0x7fffffff;
    idxr[r] = (uint32_t)(r0 + myrow + r) * (uint32_t)N_CODES + (uint32_t)(nt * 16 + n);
  }
  float4v acc2[8];
#pragma unroll
  for (int t = 0; t < 8; ++t) acc2[t] = (float4v){0.f, 0.f, 0.f, 0.f};
  float4v accP = (float4v){0.f, 0.f, 0.f, 0.f};

  const int kc = nt * 16 + n;
  const char* bbase = sm + CB1H_OFF + (kc >> 1) * CB1_BS + (kc & 1) * 512 + quad * 16;

  // ---- pipelined K-loop: iter c does GEMM1(c) ⊗ phaseC(c-1), GEMM2(c-1) ----
  for (int c = 0; c <= NCHUNK; ++c) {
    // GEMM1(c): 3 independent accumulator chains (hh/hl/lh) so phase-C VALU
    // fills the MFMA latency gaps.
    float4v hh = (float4v){0.f, 0.f, 0.f, 0.f};
    float4v hl = (float4v){0.f, 0.f, 0.f, 0.f};
    float4v lh = (float4v){0.f, 0.f, 0.f, 0.f};
    if (c < NCHUNK) {
#pragma unroll
      for (int ks = 0; ks < 8; ++ks) {
        short8 bh = *(const short8*)(bbase + ks * 64);
        short8 bl = *(const short8*)(bbase + (CB1L_OFF - CB1H_OFF) + ks * 64);
        hh = __builtin_amdgcn_mfma_f32_16x16x32_bf16(zhi[ks], bh, hh, 0, 0, 0);
        hl = __builtin_amdgcn_mfma_f32_16x16x32_bf16(zhi[ks], bl, hl, 0, 0, 0);
        lh = __builtin_amdgcn_mfma_f32_16x16x32_bf16(zlo[ks], bh, lh, 0, 0, 0);
      }
    }
    // phase C on chunk c-1 logits (accP)
    if (c > 0) {
      const int codeg0 = (c - 1) * CK + nt * 16 + n;
#pragma unroll
      for (int r = 0; r < 4; ++r) {
        float l = accP[r];
        uint32_t bits = threefry_bits(idxr[r]);
        idxr[r] += 32u;
        float u = __uint_as_float((bits >> 9) | 0x3f800000u) - 1.0f;   // [0,1)
        float h = u - 1.0f;
        float uu = fmaxf(u, 1.17549435e-38f);
        float t_hw = -0.69314718056f * __log2f(uu);
        float poly = 1.0f + h * (-0.5f + h * (0.33333333f + h * (-0.25f)));
        float t = (h > -0.015625f) ? (-h * poly) : t_hw;
        float e = __expf(l);
        skl[r] += e;
        tkl[r] = fmaf(e, l, tkl[r]);
        bool b1 = l > v1[r];
        bool b2 = l > v2[r];
        v2[r] = b1 ? v1[r] : (b2 ? l : v2[r]);
        i2[r] = b1 ? i1[r] : (b2 ? codeg0 : i2[r]);
        v1[r] = b1 ? l : v1[r];
        i1[r] = b1 ? codeg0 : i1[r];
        // exp(l + g - 12) == exp(l)/t * e^-12
        float p = e * __builtin_amdgcn_rcpf(t) * 6.1442123533282097e-06f;
        unsigned short ph = f2bf(p);
        float pfl = bf2f(ph);
        unsigned short plo = f2bf(p - pfl);
        s2l[r] += pfl + bf2f(plo);           // denominator from rounded P
        int prow = myrow + r;
        *(unsigned short*)(sm + P_OFF + prow * P_ROW + kc * 2) = ph;
        *(unsigned short*)(sm + P_OFF + P_SPLIT + prow * P_ROW + kc * 2) = plo;
      }
    }
    accP = hh + hl + lh;                     // logits(c) for next iteration

    __syncthreads();                         // B1: P ready; CB1(c) fully consumed
    // stage CB1(c+1) — drains at B2 under GEMM2
    if (c + 1 < NCHUNK) {
      const size_t k1 = (size_t)(c + 1) * CK;
#pragma unroll
      for (int i = 0; i < 4; ++i) {
        int b = wave * 4 + i;
        dma16(cbhi_b + (k1 + 2 * b) * 512 + (size_t)lane * 16, sm + CB1H_OFF + b * CB1_BS);
        dma16(cblo_b + (k1 + 2 * b) * 512 + (size_t)lane * 16, sm + CB1L_OFF + b * CB1_BS);
      }
    }
    // GEMM2(c-1): z_q += P * CBT[(c-1)&1]
    if (c > 0) {
      const char* cbtb = sm + ((c & 1) ? CBT0_OFF : CBT1_OFF);   // (c-1)&1 buffer
      short8 pah0 = *(const short8*)(sm + P_OFF + n * P_ROW + quad * 16);
      short8 pal0 = *(const short8*)(sm + P_OFF + P_SPLIT + n * P_ROW + quad * 16);
      short8 pah1 = *(const short8*)(sm + P_OFF + (16 + n) * P_ROW + quad * 16);
      short8 pal1 = *(const short8*)(sm + P_OFF + P_SPLIT + (16 + n) * P_ROW + quad * 16);
#pragma unroll
      for (int t = 0; t < 4; ++t) {
        int dt = wave * 4 + t;               // dims dt*16 .. dt*16+15
        short8 bb = *(const short8*)(cbtb + dt * 1024 + n * 64 + quad * 16);
        acc2[t * 2 + 0] = __builtin_amdgcn_mfma_f32_16x16x32_bf16(pah0, bb, acc2[t * 2 + 0], 0, 0, 0);
        acc2[t * 2 + 0] = __builtin_amdgcn_mfma_f32_16x16x32_bf16(pal0, bb, acc2[t * 2 + 0], 0, 0, 0);
        acc2[t * 2 + 1] = __builtin_amdgcn_mfma_f32_16x16x32_bf16(pah1, bb, acc2[t * 2 + 1], 0, 0, 0);
        acc2[t * 2 + 1] = __builtin_amdgcn_mfma_f32_16x16x32_bf16(pal1, bb, acc2[t * 2 + 1], 0, 0, 0);
      }
    }
    __syncthreads();                         // B2: CB1(c+1) drained; CBT[(c+1)&1] free
    // stage CBT(c+1) into the buffer GEMM2 just finished — drains at B1(c+1)
    if (c + 1 < NCHUNK) {
#pragma unroll
      for (int i = 0; i < 4; ++i) {
        int b = wave * 4 + i;
        dma16(cbt_b + (size_t)(c + 1) * 16384 + (size_t)b * 1024 + (size_t)lane * 16,
              sm + ((c & 1) ? CBT0_OFF : CBT1_OFF) + b * 1024);
      }
    }
  }

  // ================= epilogue =================
#pragma unroll
  for (int m = 1; m <= 8; m <<= 1) {
#pragma unroll
    for (int r = 0; r < 4; ++r) {
      s2l[r] += __shfl_xor(s2l[r], m);
      skl[r] += __shfl_xor(skl[r], m);
      tkl[r] += __shfl_xor(tkl[r], m);
      float ov1 = __shfl_xor(v1[r], m); int oi1 = __shfl_xor(i1[r], m);
      float ov2 = __shfl_xor(v2[r], m); int oi2 = __shfl_xor(i2[r], m);
      bool bb = (ov1 > v1[r]) || (ov1 == v1[r] && oi1 < i1[r]);
      float w1 = bb ? ov1 : v1[r]; int wi1 = bb ? oi1 : i1[r];
      float lv = bb ? v1[r] : ov1; int li = bb ? i1[r] : oi1;
      float cv = bb ? ov2 : v2[r]; int ci = bb ? oi2 : i2[r];
      bool b2 = (lv > cv) || (lv == cv && li < ci);
      v1[r] = w1; i1[r] = wi1;
      v2[r] = b2 ? lv : cv; i2[r] = b2 ? li : ci;
    }
  }
  if (n == 0) {
    int off = (nt * 32 + myrow) * 4;
    float4 fs = {s2l[0], s2l[1], s2l[2], s2l[3]};
    *(float4*)(sm + S2B_OFF + off) = fs;
    float4 fk = {skl[0], skl[1], skl[2], skl[3]};
    *(float4*)(sm + SKL_OFF + off) = fk;
    float4 ft = {tkl[0], tkl[1], tkl[2], tkl[3]};
    *(float4*)(sm + TKL_OFF + off) = ft;
    float4 f1 = {v1[0], v1[1], v1[2], v1[3]};
    *(float4*)(sm + V1B_OFF + off) = f1;
    int4 g1 = {i1[0], i1[1], i1[2], i1[3]};
    *(int4*)(sm + I1B_OFF + off) = g1;
    float4 f2 = {v2[0], v2[1], v2[2], v2[3]};
    *(float4*)(sm + V2B_OFF + off) = f2;
    int4 g2 = {i2[0], i2[1], i2[2], i2[3]};
    *(int4*)(sm + I2B_OFF + off) = g2;
  }
  // restage z fp32 tile over CB1H/CB1L region (disjoint from CBT/P/scratch)
  {
    float* zts = (float*)sm;
#pragma unroll
    for (int i = 0; i < 8; ++i) {
      int F = tid + i * 256;
      int row = F >> 6, d4 = (F & 63) * 4;
      *(float4*)(zts + row * ZT_ROWF + d4) =
          *(const float4*)(z + (size_t)(r0 + row) * DIMV + d4);
    }
  }
  __syncthreads();                           // E1

  const float* zts = (const float*)sm;
  if (tid < 32) {
    int r = tid;
    const float* sklb = (const float*)(sm + SKL_OFF);
    const float* tklb = (const float*)(sm + TKL_OFF);
    float S = sklb[r] + sklb[32 + r];
    float T = tklb[r] + tklb[32 + r];
    float klr = T / S - __logf(S) + 9.010913347279288f;   // ln(8192)
#pragma unroll
    for (int m = 1; m <= 16; m <<= 1) klr += __shfl_xor(klr, m);
    if (r == 0) atomicAdd(&wsA[0], klr);
    // candidates: top-2 from each code-parity half, refined in fp64
    int cidx[4];
    cidx[0] = *(const int*)(sm + I1B_OFF + r * 4);
    cidx[1] = *(const int*)(sm + I2B_OFF + r * 4);
    cidx[2] = *(const int*)(sm + I1B_OFF + 128 + r * 4);
    cidx[3] = *(const int*)(sm + I2B_OFF + 128 + r * 4);
    const float* zp = zts + r * ZT_ROWF;
    double best = -1.0e300;
    int bi = 0x7fffffff;
#pragma unroll
    for (int cnd = 0; cnd < 4; ++cnd) {
      const float* cp = cb + (size_t)cidx[cnd] * DIMV;
      double d = 0.0;
      for (int dd = 0; dd < DIMV; dd += 4) {
        float4 zv = *(const float4*)(zp + dd);
        float4 xv = *(const float4*)(cp + dd);
        d += (double)zv.x * xv.x + (double)zv.y * xv.y +
             (double)zv.z * xv.z + (double)zv.w * xv.w;
      }
      if (d > best || (d == best && cidx[cnd] < bi)) { best = d; bi = cidx[cnd]; }
    }
    out[OUT_CODE + (size_t)(r0 + r)] = (float)bi;
  }

  // z_q_st + commit partial
  float invm0[4], invm1[4];
  {
    const float* s2b = (const float*)(sm + S2B_OFF);
#pragma unroll
    for (int e = 0; e < 4; ++e) {
      float Sa = s2b[quad * 4 + e] + s2b[32 + quad * 4 + e];
      float Sb = s2b[16 + quad * 4 + e] + s2b[32 + 16 + quad * 4 + e];
      invm0[e] = 1.0f / Sa;
      invm1[e] = 1.0f / Sb;
    }
  }
  float cpart = 0.f;
#pragma unroll
  for (int t = 0; t < 4; ++t) {
    int dim = (wave * 4 + t) * 16 + n;
#pragma unroll
    for (int ms = 0; ms < 2; ++ms) {
      float4v a = acc2[t * 2 + ms];
#pragma unroll
      for (int e = 0; e < 4; ++e) {
        int row = ms * 16 + quad * 4 + e;
        float q = a[e] * (ms ? invm1[e] : invm0[e]);
        float zv = zts[row * ZT_ROWF + dim];
        float err = q - zv;
        cpart += err * err;
        out[(size_t)(r0 + row) * DIMV + dim] = zv + err;
      }
    }
  }
#pragma unroll
  for (int m = 1; m <= 32; m <<= 1) cpart += __shfl_xor(cpart, m);
  if (lane == 0) atomicAdd(&wsA[1], cpart);
}

// ================= fallback v1 (fp32 VALU, needs only 8B ws) =================
#define ZSTRIDE  260
#define CSTRIDE  260
#define PSTRIDE  36
#define RSTRIDE  17

__global__ __launch_bounds__(256, 2)
void vq_main_v1(const float* __restrict__ z, const float* __restrict__ cb,
                float* __restrict__ out, float* __restrict__ ws_acc) {
  __shared__ float zt[RT * ZSTRIDE];
  __shared__ float cbt[CK * CSTRIDE];
  __shared__ float ptile[RT * PSTRIDE];
  __shared__ float redb[RT * RSTRIDE];
  __shared__ float m2s[RT], s2s[RT], scls[RT];

  const int tid = threadIdx.x;
  const int r0  = blockIdx.x * RT;
#pragma unroll
  for (int p = 0; p < 8; ++p) {
    int q = tid + p * 256;
    int i = q >> 6, c4 = (q & 63) * 4;
    *(float4*)(&zt[i * ZSTRIDE + c4]) = *(const float4*)(z + (size_t)(r0 + i) * DIMV + c4);
  }
  if (tid < RT) { m2s[tid] = -INFINITY; s2s[tid] = 0.f; scls[tid] = 0.f; }
  const int tr = tid & 15, tk = tid >> 4, rowg = tid >> 6;
  const int d4 = (tid & 63) * 4;
  float c_m[2][2], c_s[2][2], c_t[2][2];
  int   c_i[2][2];
#pragma unroll
  for (int a = 0; a < 2; ++a)
#pragma unroll
    for (int b = 0; b < 2; ++b) { c_m[a][b] = -INFINITY; c_s[a][b] = 0.f; c_t[a][b] = 0.f; c_i[a][b] = 0; }
  float acc2[8][4];
#pragma unroll
  for (int j = 0; j < 8; ++j)
#pragma unroll
    for (int e = 0; e < 4; ++e) acc2[j][e] = 0.f;
  __syncthreads();
  for (int c = 0; c < NCHUNK; ++c) {
    const int k0 = c * CK;
#pragma unroll
    for (int p = 0; p < 8; ++p) {
      int q = tid + p * 256;
      int i = q >> 6, c4 = (q & 63) * 4;
      *(float4*)(&cbt[i * CSTRIDE + c4]) = *(const float4*)(cb + (size_t)(k0 + i) * DIMV + c4);
    }
    __syncthreads();
    float l00 = 0.f, l01 = 0.f, l10 = 0.f, l11 = 0.f;
    {
      const float* zp0 = &zt[tr * ZSTRIDE];
      const float* zp1 = &zt[(tr + 16) * ZSTRIDE];
      const float* bp0 = &cbt[tk * CSTRIDE];
      const float* bp1 = &cbt[(tk + 16) * CSTRIDE];
#pragma unroll 4
      for (int d = 0; d < DIMV; d += 4) {
        float4 a0 = *(const float4*)(zp0 + d);
        float4 a1 = *(const float4*)(zp1 + d);
        float4 b0 = *(const float4*)(bp0 + d);
        float4 b1 = *(const float4*)(bp1 + d);
        l00 += a0.x*b0.x + a0.y*b0.y + a0.z*b0.z + a0.w*b0.w;
        l01 += a0.x*b1.x + a0.y*b1.y + a0.z*b1.z + a0.w*b1.w;
        l10 += a1.x*b0.x + a1.y*b0.y + a1.z*b0.z + a1.w*b0.w;
        l11 += a1.x*b1.x + a1.y*b1.y + a1.z*b1.z + a1.w*b1.w;
      }
    }
    float lv2[2][2] = {{l00, l01}, {l10, l11}};
    float a2[2][2];
#pragma unroll
    for (int a = 0; a < 2; ++a) {
      int grow = r0 + tr + a * 16;
#pragma unroll
      for (int b = 0; b < 2; ++b) {
        int gk = k0 + tk + b * 16;
        float g  = gumbel_at_v1((uint32_t)grow * (uint32_t)N_CODES + (uint32_t)gk);
        float lv = lv2[a][b];
        a2[a][b] = lv + g;
        if (lv > c_m[a][b]) {
          float sc = expf(c_m[a][b] - lv);
          c_s[a][b] = c_s[a][b] * sc + 1.0f;
          c_t[a][b] = c_t[a][b] * sc + lv;
          c_m[a][b] = lv;
          c_i[a][b] = gk;
        } else {
          float e = expf(lv - c_m[a][b]);
          c_s[a][b] += e;
          c_t[a][b] += e * lv;
        }
      }
    }
    redb[tr * RSTRIDE + tk]        = fmaxf(a2[0][0], a2[0][1]);
    redb[(tr + 16) * RSTRIDE + tk] = fmaxf(a2[1][0], a2[1][1]);
    __syncthreads();
    if (tid < RT) {
      float cm = -INFINITY;
#pragma unroll
      for (int j = 0; j < 16; ++j) cm = fmaxf(cm, redb[tid * RSTRIDE + j]);
      float m2n = fmaxf(m2s[tid], cm);
      scls[tid] = expf(m2s[tid] - m2n);
      m2s[tid]  = m2n;
    }
    __syncthreads();
#pragma unroll
    for (int a = 0; a < 2; ++a) {
      int row = tr + a * 16;
      float m2r = m2s[row];
      float p0 = expf(a2[a][0] - m2r);
      float p1 = expf(a2[a][1] - m2r);
      ptile[row * PSTRIDE + tk]      = p0;
      ptile[row * PSTRIDE + tk + 16] = p1;
      redb[row * RSTRIDE + tk] = p0 + p1;
    }
    __syncthreads();
    if (tid < RT) {
      float ss = 0.f;
#pragma unroll
      for (int j = 0; j < 16; ++j) ss += redb[tid * RSTRIDE + j];
      s2s[tid] = s2s[tid] * scls[tid] + ss;
    }
#pragma unroll
    for (int j = 0; j < 8; ++j) {
      float sc = scls[rowg * 8 + j];
      acc2[j][0] *= sc; acc2[j][1] *= sc; acc2[j][2] *= sc; acc2[j][3] *= sc;
    }
    for (int k4 = 0; k4 < CK; k4 += 4) {
      float4 cb0 = *(const float4*)(&cbt[(k4 + 0) * CSTRIDE + d4]);
      float4 cb1v = *(const float4*)(&cbt[(k4 + 1) * CSTRIDE + d4]);
      float4 cb2 = *(const float4*)(&cbt[(k4 + 2) * CSTRIDE + d4]);
      float4 cb3 = *(const float4*)(&cbt[(k4 + 3) * CSTRIDE + d4]);
#pragma unroll
      for (int j = 0; j < 8; ++j) {
        float4 p4 = *(const float4*)(&ptile[(rowg * 8 + j) * PSTRIDE + k4]);
        acc2[j][0] += p4.x*cb0.x + p4.y*cb1v.x + p4.z*cb2.x + p4.w*cb3.x;
        acc2[j][1] += p4.x*cb0.y + p4.y*cb1v.y + p4.z*cb2.y + p4.w*cb3.y;
        acc2[j][2] += p4.x*cb0.z + p4.y*cb1v.z + p4.z*cb2.z + p4.w*cb3.z;
        acc2[j][3] += p4.x*cb0.w + p4.y*cb1v.w + p4.z*cb2.w + p4.w*cb3.w;
      }
    }
    __syncthreads();
  }
  float* kbuf = cbt;
#pragma unroll
  for (int a = 0; a < 2; ++a) {
    float m0 = c_m[a][0], m1v = c_m[a][1];
    float m, s, t; int bi;
    if (m0 >= m1v) {
      float e = expf(m1v - m0);
      m = m0; s = c_s[a][0] + c_s[a][1] * e; t = c_t[a][0] + c_t[a][1] * e;
    } else {
      float e = expf(m0 - m1v);
      m = m1v; s = c_s[a][0] * e + c_s[a][1]; t = c_t[a][0] * e + c_t[a][1];
    }
    if (m0 > m1v)      bi = c_i[a][0];
    else if (m1v > m0) bi = c_i[a][1];
    else               bi = min(c_i[a][0], c_i[a][1]);
    int row = tr + a * 16;
    kbuf[row * 65 + tk * 4 + 0] = m;
    kbuf[row * 65 + tk * 4 + 1] = s;
    kbuf[row * 65 + tk * 4 + 2] = t;
    kbuf[row * 65 + tk * 4 + 3] = (float)bi;
  }
  __syncthreads();
  if (tid < RT) {
    int r = tid;
    float M = -INFINITY, S = 0.f, T = 0.f, BM = -INFINITY;
    int BI = 0x7fffffff;
    for (int j = 0; j < 16; ++j) {
      float m  = kbuf[r * 65 + j * 4 + 0];
      float s  = kbuf[r * 65 + j * 4 + 1];
      float t  = kbuf[r * 65 + j * 4 + 2];
      int   bi = (int)kbuf[r * 65 + j * 4 + 3];
      if (m <= M) {
        float e = expf(m - M);
        S += s * e; T += t * e;
      } else {
        float e = expf(M - m);
        S = S * e + s; T = T * e + t; M = m;
      }
      if (m > BM || (m == BM && bi < BI)) { BM = m; BI = bi; }
    }
    float kl = logf((float)N_CODES) + T / S - M - logf(S);
    atomicAdd(&ws_acc[0], kl);
    out[OUT_CODE + (size_t)(r0 + r)] = (float)BI;
  }
  float cpart = 0.f;
#pragma unroll
  for (int j = 0; j < 8; ++j) {
    int row  = rowg * 8 + j;
    int grow = r0 + row;
    float inv = 1.0f / s2s[row];
    float4 zv = *(const float4*)(&zt[row * ZSTRIDE + d4]);
    float q0 = acc2[j][0] * inv, q1 = acc2[j][1] * inv;
    float q2 = acc2[j][2] * inv, q3 = acc2[j][3] * inv;
    float e0 = q0 - zv.x, e1 = q1 - zv.y, e2 = q2 - zv.z, e3 = q3 - zv.w;
    cpart += e0*e0 + e1*e1 + e2*e2 + e3*e3;
    float4 o;
    o.x = zv.x + e0; o.y = zv.y + e1; o.z = zv.z + e2; o.w = zv.w + e3;
    *(float4*)(&out[(size_t)grow * DIMV + d4]) = o;
  }
#pragma unroll
  for (int off = 32; off > 0; off >>= 1) cpart += __shfl_down(cpart, off, 64);
  __syncthreads();
  if ((tid & 63) == 0) redb[tid >> 6] = cpart;
  __syncthreads();
  if (tid == 0) {
    float cs = redb[0] + redb[1] + redb[2] + redb[3];
    atomicAdd(&ws_acc[1], cs);
  }
}

__global__ void vq_finalize(const float* __restrict__ ws_acc, float* __restrict__ out) {
  if (threadIdx.x == 0 && blockIdx.x == 0) {
    float kl = 0.01f * (ws_acc[0] / (float)N_ROWS);
    float cm = 0.25f * (ws_acc[1] / (float)OUT_ZQ_N);
    out[OUT_LOSS] = cm + kl;
  }
}

extern "C" void kernel_launch(void* const* d_in, const int* in_sizes, int n_in,
                              void* d_out, int out_size, void* d_ws, size_t ws_size,
                              hipStream_t stream) {
  (void)in_sizes; (void)n_in; (void)out_size;
  const float* z  = (const float*)d_in[0];
  const float* cb = (const float*)d_in[1];
  float* out = (float*)d_out;
  if (ws_size >= (size_t)WS_NEED) {
    char* ws = (char*)d_ws;
    hipMemsetAsync(ws + WS_ACC, 0, 8, stream);
    vq_prep<<<256, 256, 0, stream>>>(cb, ws);
    vq_main_v2<<<N_ROWS / RT, 256, 0, stream>>>(z, cb, out, ws);
    vq_finalize<<<1, 64, 0, stream>>>((const float*)(ws + WS_ACC), out);
  } else {
    float* ws = (float*)d_ws;
    hipMemsetAsync(ws, 0, 8, stream);
    vq_main_v1<<<N_ROWS / RT, 256, 0, stream>>>(z, cb, out, ws);
    vq_finalize<<<1, 64, 0, stream>>>(ws, out);
  }
}

// Round 5
// 833.996 us; speedup vs baseline: 1.0803x; 1.0803x over previous
//
#include <hip/hip_runtime.h>
#include <stdint.h>
#include <math.h>

// ---------------- problem constants ----------------
#define N_ROWS   16384
#define N_CODES  8192
#define DIMV     256
#define RT       32
#define CK       32
#define NCHUNK   (N_CODES / CK)
#define OUT_ZQ_N ((size_t)N_ROWS * DIMV)
#define OUT_LOSS OUT_ZQ_N
#define OUT_CODE (OUT_ZQ_N + 1)

// ---------------- workspace layout ----------------
#define WS_CBHI 0u
#define WS_CBLO 4194304u
#define WS_CBT  8388608u
#define WS_ACC  12582912u
#define WS_NEED (12582912u + 64u)

// ---------------- LDS layout (bytes) ----------------
// CB1: 16 blocks of 1024B (2 codes x 512B) at stride 1040. Single-buffered;
//   DMA issued after S4, drained at S0 behind GEMM2.
// CBT: 16 blocks of 1024B at stride 1024, DOUBLE buffered; DMA issued after
//   S0 into alt buffer, drained at S4 behind GEMM1+phaseC (fully hidden).
// P: hi-only bf16 [32 rows][40 ushort].
#define CB1H_OFF  0
#define CB1L_OFF  16640
#define CB1_BS    1040
#define CBT0_OFF  33280
#define CBT1_OFF  49664
#define P_OFF     66048
#define P_ROW     80
#define S2B_OFF   68608    // [2][32] f32
#define SKL_OFF   68864
#define TKL_OFF   69120
#define V1B_OFF   69376
#define I1B_OFF   69632
#define V2B_OFF   69888
#define I2B_OFF   70144
#define SMEM_BYTES 70400
#define ZT_ROWF   260      // z fp32 tile stride (floats), overlays 0..33280

typedef __attribute__((ext_vector_type(8))) short short8;
typedef __attribute__((ext_vector_type(4))) float float4v;

typedef __attribute__((address_space(1))) uint32_t g_u32;
typedef __attribute__((address_space(3))) uint32_t l_u32;

// async global->LDS DMA, 16B/lane; LDS dest = wave-uniform base + lane*16
__device__ __forceinline__ void dma16(const void* gsrc, void* ldst) {
  __builtin_amdgcn_global_load_lds((g_u32*)gsrc, (l_u32*)ldst, 16, 0, 0);
}

__device__ __forceinline__ uint32_t rotl32(uint32_t x, int r) {
  return __builtin_rotateleft32(x, (uint32_t)r);
}

// Threefry-2x32, key=(0,42), counter=(0, c); out0^out1 (JAX partitionable).
__device__ __forceinline__ uint32_t threefry_bits(uint32_t c) {
  const uint32_t k0 = 0u, k1 = 42u;
  const uint32_t k2 = 0x1BD11BDAu ^ k0 ^ k1;
  uint32_t x0 = 0u + k0;
  uint32_t x1 = c + k1;
#define TF_R(r) { x0 += x1; x1 = rotl32(x1, r); x1 ^= x0; }
  TF_R(13) TF_R(15) TF_R(26) TF_R(6)
  x0 += k1; x1 += k2 + 1u;
  TF_R(17) TF_R(29) TF_R(16) TF_R(24)
  x0 += k2; x1 += k0 + 2u;
  TF_R(13) TF_R(15) TF_R(26) TF_R(6)
  x0 += k0; x1 += k1 + 3u;
  TF_R(17) TF_R(29) TF_R(16) TF_R(24)
  x0 += k1; x1 += k2 + 4u;
  TF_R(13) TF_R(15) TF_R(26) TF_R(6)
  x0 += k2; x1 += k0 + 5u;
#undef TF_R
  return x0 ^ x1;
}

// accurate gumbel for the v1 fallback path
__device__ __forceinline__ float gumbel_at_v1(uint32_t idx) {
  uint32_t bits = threefry_bits(idx);
  float u = __uint_as_float((bits >> 9) | 0x3f800000u) - 1.0f;
  u = fmaxf(u, 1.17549435e-38f);
  return -logf(-logf(u));
}

__device__ __forceinline__ unsigned short f2bf(float x) {
  uint32_t u = __float_as_uint(x);
  u += 0x7fffu + ((u >> 16) & 1u);
  return (unsigned short)(u >> 16);
}
__device__ __forceinline__ float bf2f(unsigned short h) {
  return __uint_as_float(((uint32_t)h) << 16);
}

// ================= prep: cb fp32 -> bf16 hi/lo + chunk-blocked transpose =================
__global__ __launch_bounds__(256)
void vq_prep(const float* __restrict__ cb, char* __restrict__ ws) {
  __shared__ unsigned short lhs[32 * 260];
  const int c = blockIdx.x;
  const int tid = threadIdx.x;
  const int k0 = c * 32;
  unsigned short* cbhi = (unsigned short*)(ws + WS_CBHI);
  unsigned short* cblo = (unsigned short*)(ws + WS_CBLO);
  unsigned short* cbt  = (unsigned short*)(ws + WS_CBT);
#pragma unroll
  for (int i = 0; i < 8; ++i) {
    int F = tid + i * 256;
    int code = F >> 6, d4 = (F & 63) * 4;
    float4 v = *(const float4*)(cb + (size_t)(k0 + code) * DIMV + d4);
    unsigned short h0 = f2bf(v.x), h1 = f2bf(v.y), h2 = f2bf(v.z), h3 = f2bf(v.w);
    unsigned short l0 = f2bf(v.x - bf2f(h0)), l1 = f2bf(v.y - bf2f(h1));
    unsigned short l2 = f2bf(v.z - bf2f(h2)), l3 = f2bf(v.w - bf2f(h3));
    ushort4 hv = {h0, h1, h2, h3};
    ushort4 lv = {l0, l1, l2, l3};
    *(ushort4*)(cbhi + (size_t)(k0 + code) * DIMV + d4) = hv;
    *(ushort4*)(cblo + (size_t)(k0 + code) * DIMV + d4) = lv;
    *(ushort4*)(&lhs[code * 260 + d4]) = hv;
  }
  __syncthreads();
  const int d = tid;
  unsigned short vals[32];
#pragma unroll
  for (int cc = 0; cc < 32; ++cc) vals[cc] = lhs[cc * 260 + d];
  unsigned short* base = cbt + (size_t)c * 8192 + (size_t)d * 32;
#pragma unroll
  for (int j = 0; j < 8; ++j) {
    ushort4 w = {vals[4 * j], vals[4 * j + 1], vals[4 * j + 2], vals[4 * j + 3]};
    *(ushort4*)(base + j * 4) = w;
  }
}

// ================= main v5: serial phases, P-hi-only GEMM2, hidden CBT dbuf =================
__global__ __launch_bounds__(256, 2)
void vq_main_v2(const float* __restrict__ z, const float* __restrict__ cb,
                float* __restrict__ out, char* __restrict__ ws) {
  __shared__ __align__(16) char sm[SMEM_BYTES];
  const int tid  = threadIdx.x;
  const int wave = tid >> 6;
  const int lane = tid & 63;
  const int quad = lane >> 4;
  const int n    = lane & 15;
  const int mt   = wave & 1;
  const int nt   = wave >> 1;
  const int r0   = blockIdx.x * RT;
  const int myrow = mt * 16 + quad * 4;      // C-layout base row
  const char* cbhi_b = ws + WS_CBHI;
  const char* cblo_b = ws + WS_CBLO;
  const char* cbt_b  = ws + WS_CBT;
  float* wsA = (float*)(ws + WS_ACC);

  // ---- prologue: stage z fp32 tile, build A-fragments in registers ----
  {
    float* zts = (float*)sm;
#pragma unroll
    for (int i = 0; i < 8; ++i) {
      int F = tid + i * 256;
      int row = F >> 6, d4 = (F & 63) * 4;
      *(float4*)(zts + row * ZT_ROWF + d4) =
          *(const float4*)(z + (size_t)(r0 + row) * DIMV + d4);
    }
  }
  __syncthreads();
  short8 zhi[8], zlo[8];
  {
    const float* zts = (const float*)sm;
    const int rowl = mt * 16 + n;            // A-frag m = lane&15
#pragma unroll
    for (int ks = 0; ks < 8; ++ks) {
      const float* zp = zts + rowl * ZT_ROWF + ks * 32 + quad * 8;
      float4 f0 = *(const float4*)zp;
      float4 f1 = *(const float4*)(zp + 4);
      float ff0[4] = {f0.x, f0.y, f0.z, f0.w};
      float ff1[4] = {f1.x, f1.y, f1.z, f1.w};
#pragma unroll
      for (int j = 0; j < 4; ++j) {
        unsigned short h = f2bf(ff0[j]);
        zhi[ks][j] = (short)h;
        zlo[ks][j] = (short)f2bf(ff0[j] - bf2f(h));
      }
#pragma unroll
      for (int j = 0; j < 4; ++j) {
        unsigned short h = f2bf(ff1[j]);
        zhi[ks][4 + j] = (short)h;
        zlo[ks][4 + j] = (short)f2bf(ff1[j] - bf2f(h));
      }
    }
  }
  __syncthreads();   // all waves done reading z-tile (CB1 region reuse)

  // ---- prologue staging: CB1(0) + CBT(0) -> buf0 (drained at first S0) ----
#pragma unroll
  for (int i = 0; i < 4; ++i) {
    int b = wave * 4 + i;
    dma16(cbhi_b + (size_t)(2 * b) * 512 + (size_t)lane * 16, sm + CB1H_OFF + b * CB1_BS);
    dma16(cblo_b + (size_t)(2 * b) * 512 + (size_t)lane * 16, sm + CB1L_OFF + b * CB1_BS);
    dma16(cbt_b + (size_t)b * 1024 + (size_t)lane * 16, sm + CBT0_OFF + b * 1024);
  }

  // ---- per-lane persistent state ----
  float skl[4] = {0.f, 0.f, 0.f, 0.f};
  float tkl[4] = {0.f, 0.f, 0.f, 0.f};
  float s2l[4] = {0.f, 0.f, 0.f, 0.f};
  float v1[4], v2[4];
  int   i1[4], i2[4];
  uint32_t idxr[4];
#pragma unroll
  for (int r = 0; r < 4; ++r) {
    v1[r] = -INFINITY; v2[r] = -INFINITY;
    i1[r] = 0x7fffffff; i2[r] = 0x7fffffff;
    idxr[r] = (uint32_t)(r0 + myrow + r) * (uint32_t)N_CODES + (uint32_t)(nt * 16 + n);
  }
  float4v acc2[8];
#pragma unroll
  for (int t = 0; t < 8; ++t) acc2[t] = (float4v){0.f, 0.f, 0.f, 0.f};

  const int kc = nt * 16 + n;
  const char* bbase = sm + CB1H_OFF + (kc >> 1) * CB1_BS + (kc & 1) * 512 + quad * 16;

  for (int c = 0; c < NCHUNK; ++c) {
    __syncthreads();   // S0: drains CB1(c) DMA (behind GEMM2(c-1)); CBT alt buf free

    // stage CBT(c+1) -> alt buffer; drains at S4 behind GEMM1+phaseC (hidden)
    if (c + 1 < NCHUNK) {
#pragma unroll
      for (int i = 0; i < 4; ++i) {
        int b = wave * 4 + i;
        dma16(cbt_b + (size_t)(c + 1) * 16384 + (size_t)b * 1024 + (size_t)lane * 16,
              sm + (((c + 1) & 1) ? CBT1_OFF : CBT0_OFF) + b * 1024);
      }
    }

    // ---- GEMM1: logits 16x16 tile per wave, 3-term split, 3 indep chains ----
    float4v hh = (float4v){0.f, 0.f, 0.f, 0.f};
    float4v hl = (float4v){0.f, 0.f, 0.f, 0.f};
    float4v lh = (float4v){0.f, 0.f, 0.f, 0.f};
#pragma unroll
    for (int ks = 0; ks < 8; ++ks) {
      short8 bh = *(const short8*)(bbase + ks * 64);
      short8 bl = *(const short8*)(bbase + (CB1L_OFF - CB1H_OFF) + ks * 64);
      hh = __builtin_amdgcn_mfma_f32_16x16x32_bf16(zhi[ks], bh, hh, 0, 0, 0);
      hl = __builtin_amdgcn_mfma_f32_16x16x32_bf16(zhi[ks], bl, hl, 0, 0, 0);
      lh = __builtin_amdgcn_mfma_f32_16x16x32_bf16(zlo[ks], bh, lh, 0, 0, 0);
    }
    float4v acc1 = hh + hl + lh;

    // ---- phase C: threefry, KL stats, top2, P-hi write ----
    const int codeg0 = c * CK + kc;
#pragma unroll
    for (int r = 0; r < 4; ++r) {
      float l = acc1[r];
      uint32_t bits = threefry_bits(idxr[r]);
      idxr[r] += 32u;
      float u = __uint_as_float((bits >> 9) | 0x3f800000u) - 1.0f;   // [0,1)
      float h = u - 1.0f;
      float uu = fmaxf(u, 1.17549435e-38f);
      float t_hw = -0.69314718056f * __log2f(uu);
      float poly = 1.0f + h * (-0.5f + h * (0.33333333f + h * (-0.25f)));
      float t = (h > -0.015625f) ? (-h * poly) : t_hw;
      float e = __expf(l);
      skl[r] += e;
      tkl[r] = fmaf(e, l, tkl[r]);
      bool b1 = l > v1[r];
      bool b2 = l > v2[r];
      v2[r] = b1 ? v1[r] : (b2 ? l : v2[r]);
      i2[r] = b1 ? i1[r] : (b2 ? codeg0 : i2[r]);
      v1[r] = b1 ? l : v1[r];
      i1[r] = b1 ? codeg0 : i1[r];
      // exp(l + g - 12) == exp(l)/t * e^-12 ; P stored hi-only bf16
      float p = e * __builtin_amdgcn_rcpf(t) * 6.1442123533282097e-06f;
      unsigned short ph = f2bf(p);
      s2l[r] += bf2f(ph);                  // denominator from rounded P
      *(unsigned short*)(sm + P_OFF + (myrow + r) * P_ROW + kc * 2) = ph;
    }
    __syncthreads();   // S4: P ready; CBT(c+1) arrived (hidden drain)

    // stage CB1(c+1); drains at S0(c+1) behind GEMM2 (~200cyc exposed)
    if (c + 1 < NCHUNK) {
      const size_t k1 = (size_t)(c + 1) * CK;
#pragma unroll
      for (int i = 0; i < 4; ++i) {
        int b = wave * 4 + i;
        dma16(cbhi_b + (k1 + 2 * b) * 512 + (size_t)lane * 16, sm + CB1H_OFF + b * CB1_BS);
        dma16(cblo_b + (k1 + 2 * b) * 512 + (size_t)lane * 16, sm + CB1L_OFF + b * CB1_BS);
      }
    }

    // ---- GEMM2: z_q += P_hi * CBT[c&1] ----
    {
      const char* cbtb = sm + ((c & 1) ? CBT1_OFF : CBT0_OFF);
      short8 pah0 = *(const short8*)(sm + P_OFF + n * P_ROW + quad * 16);
      short8 pah1 = *(const short8*)(sm + P_OFF + (16 + n) * P_ROW + quad * 16);
#pragma unroll
      for (int t = 0; t < 4; ++t) {
        int dt = wave * 4 + t;               // dims dt*16 .. dt*16+15
        short8 bb = *(const short8*)(cbtb + dt * 1024 + n * 64 + quad * 16);
        acc2[t * 2 + 0] = __builtin_amdgcn_mfma_f32_16x16x32_bf16(pah0, bb, acc2[t * 2 + 0], 0, 0, 0);
        acc2[t * 2 + 1] = __builtin_amdgcn_mfma_f32_16x16x32_bf16(pah1, bb, acc2[t * 2 + 1], 0, 0, 0);
      }
    }
  }

  // ================= epilogue =================
#pragma unroll
  for (int m = 1; m <= 8; m <<= 1) {
#pragma unroll
    for (int r = 0; r < 4; ++r) {
      s2l[r] += __shfl_xor(s2l[r], m);
      skl[r] += __shfl_xor(skl[r], m);
      tkl[r] += __shfl_xor(tkl[r], m);
      float ov1 = __shfl_xor(v1[r], m); int oi1 = __shfl_xor(i1[r], m);
      float ov2 = __shfl_xor(v2[r], m); int oi2 = __shfl_xor(i2[r], m);
      bool bb = (ov1 > v1[r]) || (ov1 == v1[r] && oi1 < i1[r]);
      float w1 = bb ? ov1 : v1[r]; int wi1 = bb ? oi1 : i1[r];
      float lv = bb ? v1[r] : ov1; int li = bb ? i1[r] : oi1;
      float cv = bb ? ov2 : v2[r]; int ci = bb ? oi2 : i2[r];
      bool b2 = (lv > cv) || (lv == cv && li < ci);
      v1[r] = w1; i1[r] = wi1;
      v2[r] = b2 ? lv : cv; i2[r] = b2 ? li : ci;
    }
  }
  if (n == 0) {
    int off = (nt * 32 + myrow) * 4;
    float4 fs = {s2l[0], s2l[1], s2l[2], s2l[3]};
    *(float4*)(sm + S2B_OFF + off) = fs;
    float4 fk = {skl[0], skl[1], skl[2], skl[3]};
    *(float4*)(sm + SKL_OFF + off) = fk;
    float4 ft = {tkl[0], tkl[1], tkl[2], tkl[3]};
    *(float4*)(sm + TKL_OFF + off) = ft;
    float4 f1 = {v1[0], v1[1], v1[2], v1[3]};
    *(float4*)(sm + V1B_OFF + off) = f1;
    int4 g1 = {i1[0], i1[1], i1[2], i1[3]};
    *(int4*)(sm + I1B_OFF + off) = g1;
    float4 f2 = {v2[0], v2[1], v2[2], v2[3]};
    *(float4*)(sm + V2B_OFF + off) = f2;
    int4 g2 = {i2[0], i2[1], i2[2], i2[3]};
    *(int4*)(sm + I2B_OFF + off) = g2;
  }
  // restage z fp32 tile over CB1H/CB1L region (disjoint from CBT/P/scratch)
  {
    float* zts = (float*)sm;
#pragma unroll
    for (int i = 0; i < 8; ++i) {
      int F = tid + i * 256;
      int row = F >> 6, d4 = (F & 63) * 4;
      *(float4*)(zts + row * ZT_ROWF + d4) =
          *(const float4*)(z + (size_t)(r0 + row) * DIMV + d4);
    }
  }
  __syncthreads();                           // E1

  const float* zts = (const float*)sm;
  if (tid < 32) {
    int r = tid;
    const float* sklb = (const float*)(sm + SKL_OFF);
    const float* tklb = (const float*)(sm + TKL_OFF);
    float S = sklb[r] + sklb[32 + r];
    float T = tklb[r] + tklb[32 + r];
    float klr = T / S - __logf(S) + 9.010913347279288f;   // ln(8192)
#pragma unroll
    for (int m = 1; m <= 16; m <<= 1) klr += __shfl_xor(klr, m);
    if (r == 0) atomicAdd(&wsA[0], klr);
    // candidates: top-2 from each code-parity half, refined in fp64
    int cidx[4];
    cidx[0] = *(const int*)(sm + I1B_OFF + r * 4);
    cidx[1] = *(const int*)(sm + I2B_OFF + r * 4);
    cidx[2] = *(const int*)(sm + I1B_OFF + 128 + r * 4);
    cidx[3] = *(const int*)(sm + I2B_OFF + 128 + r * 4);
    const float* zp = zts + r * ZT_ROWF;
    double best = -1.0e300;
    int bi = 0x7fffffff;
#pragma unroll
    for (int cnd = 0; cnd < 4; ++cnd) {
      const float* cp = cb + (size_t)cidx[cnd] * DIMV;
      double d = 0.0;
      for (int dd = 0; dd < DIMV; dd += 4) {
        float4 zv = *(const float4*)(zp + dd);
        float4 xv = *(const float4*)(cp + dd);
        d += (double)zv.x * xv.x + (double)zv.y * xv.y +
             (double)zv.z * xv.z + (double)zv.w * xv.w;
      }
      if (d > best || (d == best && cidx[cnd] < bi)) { best = d; bi = cidx[cnd]; }
    }
    out[OUT_CODE + (size_t)(r0 + r)] = (float)bi;
  }

  // z_q_st + commit partial
  float invm0[4], invm1[4];
  {
    const float* s2b = (const float*)(sm + S2B_OFF);
#pragma unroll
    for (int e = 0; e < 4; ++e) {
      float Sa = s2b[quad * 4 + e] + s2b[32 + quad * 4 + e];
      float Sb = s2b[16 + quad * 4 + e] + s2b[32 + 16 + quad * 4 + e];
      invm0[e] = 1.0f / Sa;
      invm1[e] = 1.0f / Sb;
    }
  }
  float cpart = 0.f;
#pragma unroll
  for (int t = 0; t < 4; ++t) {
    int dim = (wave * 4 + t) * 16 + n;
#pragma unroll
    for (int ms = 0; ms < 2; ++ms) {
      float4v a = acc2[t * 2 + ms];
#pragma unroll
      for (int e = 0; e < 4; ++e) {
        int row = ms * 16 + quad * 4 + e;
        float q = a[e] * (ms ? invm1[e] : invm0[e]);
        float zv = zts[row * ZT_ROWF + dim];
        float err = q - zv;
        cpart += err * err;
        out[(size_t)(r0 + row) * DIMV + dim] = zv + err;
      }
    }
  }
#pragma unroll
  for (int m = 1; m <= 32; m <<= 1) cpart += __shfl_xor(cpart, m);
  if (lane == 0) atomicAdd(&wsA[1], cpart);
}

// ================= fallback v1 (fp32 VALU, needs only 8B ws) =================
#define ZSTRIDE  260
#define CSTRIDE  260
#define PSTRIDE  36
#define RSTRIDE  17

__global__ __launch_bounds__(256, 2)
void vq_main_v1(const float* __restrict__ z, const float* __restrict__ cb,
                float* __restrict__ out, float* __restrict__ ws_acc) {
  __shared__ float zt[RT * ZSTRIDE];
  __shared__ float cbt[CK * CSTRIDE];
  __shared__ float ptile[RT * PSTRIDE];
  __shared__ float redb[RT * RSTRIDE];
  __shared__ float m2s[RT], s2s[RT], scls[RT];

  const int tid = threadIdx.x;
  const int r0  = blockIdx.x * RT;
#pragma unroll
  for (int p = 0; p < 8; ++p) {
    int q = tid + p * 256;
    int i = q >> 6, c4 = (q & 63) * 4;
    *(float4*)(&zt[i * ZSTRIDE + c4]) = *(const float4*)(z + (size_t)(r0 + i) * DIMV + c4);
  }
  if (tid < RT) { m2s[tid] = -INFINITY; s2s[tid] = 0.f; scls[tid] = 0.f; }
  const int tr = tid & 15, tk = tid >> 4, rowg = tid >> 6;
  const int d4 = (tid & 63) * 4;
  float c_m[2][2], c_s[2][2], c_t[2][2];
  int   c_i[2][2];
#pragma unroll
  for (int a = 0; a < 2; ++a)
#pragma unroll
    for (int b = 0; b < 2; ++b) { c_m[a][b] = -INFINITY; c_s[a][b] = 0.f; c_t[a][b] = 0.f; c_i[a][b] = 0; }
  float acc2[8][4];
#pragma unroll
  for (int j = 0; j < 8; ++j)
#pragma unroll
    for (int e = 0; e < 4; ++e) acc2[j][e] = 0.f;
  __syncthreads();
  for (int c = 0; c < NCHUNK; ++c) {
    const int k0 = c * CK;
#pragma unroll
    for (int p = 0; p < 8; ++p) {
      int q = tid + p * 256;
      int i = q >> 6, c4 = (q & 63) * 4;
      *(float4*)(&cbt[i * CSTRIDE + c4]) = *(const float4*)(cb + (size_t)(k0 + i) * DIMV + c4);
    }
    __syncthreads();
    float l00 = 0.f, l01 = 0.f, l10 = 0.f, l11 = 0.f;
    {
      const float* zp0 = &zt[tr * ZSTRIDE];
      const float* zp1 = &zt[(tr + 16) * ZSTRIDE];
      const float* bp0 = &cbt[tk * CSTRIDE];
      const float* bp1 = &cbt[(tk + 16) * CSTRIDE];
#pragma unroll 4
      for (int d = 0; d < DIMV; d += 4) {
        float4 a0 = *(const float4*)(zp0 + d);
        float4 a1 = *(const float4*)(zp1 + d);
        float4 b0 = *(const float4*)(bp0 + d);
        float4 b1 = *(const float4*)(bp1 + d);
        l00 += a0.x*b0.x + a0.y*b0.y + a0.z*b0.z + a0.w*b0.w;
        l01 += a0.x*b1.x + a0.y*b1.y + a0.z*b1.z + a0.w*b1.w;
        l10 += a1.x*b0.x + a1.y*b0.y + a1.z*b0.z + a1.w*b0.w;
        l11 += a1.x*b1.x + a1.y*b1.y + a1.z*b1.z + a1.w*b1.w;
      }
    }
    float lv2[2][2] = {{l00, l01}, {l10, l11}};
    float a2[2][2];
#pragma unroll
    for (int a = 0; a < 2; ++a) {
      int grow = r0 + tr + a * 16;
#pragma unroll
      for (int b = 0; b < 2; ++b) {
        int gk = k0 + tk + b * 16;
        float g  = gumbel_at_v1((uint32_t)grow * (uint32_t)N_CODES + (uint32_t)gk);
        float lv = lv2[a][b];
        a2[a][b] = lv + g;
        if (lv > c_m[a][b]) {
          float sc = expf(c_m[a][b] - lv);
          c_s[a][b] = c_s[a][b] * sc + 1.0f;
          c_t[a][b] = c_t[a][b] * sc + lv;
          c_m[a][b] = lv;
          c_i[a][b] = gk;
        } else {
          float e = expf(lv - c_m[a][b]);
          c_s[a][b] += e;
          c_t[a][b] += e * lv;
        }
      }
    }
    redb[tr * RSTRIDE + tk]        = fmaxf(a2[0][0], a2[0][1]);
    redb[(tr + 16) * RSTRIDE + tk] = fmaxf(a2[1][0], a2[1][1]);
    __syncthreads();
    if (tid < RT) {
      float cm = -INFINITY;
#pragma unroll
      for (int j = 0; j < 16; ++j) cm = fmaxf(cm, redb[tid * RSTRIDE + j]);
      float m2n = fmaxf(m2s[tid], cm);
      scls[tid] = expf(m2s[tid] - m2n);
      m2s[tid]  = m2n;
    }
    __syncthreads();
#pragma unroll
    for (int a = 0; a < 2; ++a) {
      int row = tr + a * 16;
      float m2r = m2s[row];
      float p0 = expf(a2[a][0] - m2r);
      float p1 = expf(a2[a][1] - m2r);
      ptile[row * PSTRIDE + tk]      = p0;
      ptile[row * PSTRIDE + tk + 16] = p1;
      redb[row * RSTRIDE + tk] = p0 + p1;
    }
    __syncthreads();
    if (tid < RT) {
      float ss = 0.f;
#pragma unroll
      for (int j = 0; j < 16; ++j) ss += redb[tid * RSTRIDE + j];
      s2s[tid] = s2s[tid] * scls[tid] + ss;
    }
#pragma unroll
    for (int j = 0; j < 8; ++j) {
      float sc = scls[rowg * 8 + j];
      acc2[j][0] *= sc; acc2[j][1] *= sc; acc2[j][2] *= sc; acc2[j][3] *= sc;
    }
    for (int k4 = 0; k4 < CK; k4 += 4) {
      float4 cb0 = *(const float4*)(&cbt[(k4 + 0) * CSTRIDE + d4]);
      float4 cb1v = *(const float4*)(&cbt[(k4 + 1) * CSTRIDE + d4]);
      float4 cb2 = *(const float4*)(&cbt[(k4 + 2) * CSTRIDE + d4]);
      float4 cb3 = *(const float4*)(&cbt[(k4 + 3) * CSTRIDE + d4]);
#pragma unroll
      for (int j = 0; j < 8; ++j) {
        float4 p4 = *(const float4*)(&ptile[(rowg * 8 + j) * PSTRIDE + k4]);
        acc2[j][0] += p4.x*cb0.x + p4.y*cb1v.x + p4.z*cb2.x + p4.w*cb3.x;
        acc2[j][1] += p4.x*cb0.y + p4.y*cb1v.y + p4.z*cb2.y + p4.w*cb3.y;
        acc2[j][2] += p4.x*cb0.z + p4.y*cb1v.z + p4.z*cb2.z + p4.w*cb3.z;
        acc2[j][3] += p4.x*cb0.w + p4.y*cb1v.w + p4.z*cb2.w + p4.w*cb3.w;
      }
    }
    __syncthreads();
  }
  float* kbuf = cbt;
#pragma unroll
  for (int a = 0; a < 2; ++a) {
    float m0 = c_m[a][0], m1v = c_m[a][1];
    float m, s, t; int bi;
    if (m0 >= m1v) {
      float e = expf(m1v - m0);
      m = m0; s = c_s[a][0] + c_s[a][1] * e; t = c_t[a][0] + c_t[a][1] * e;
    } else {
      float e = expf(m0 - m1v);
      m = m1v; s = c_s[a][0] * e + c_s[a][1]; t = c_t[a][0] * e + c_t[a][1];
    }
    if (m0 > m1v)      bi = c_i[a][0];
    else if (m1v > m0) bi = c_i[a][1];
    else               bi = min(c_i[a][0], c_i[a][1]);
    int row = tr + a * 16;
    kbuf[row * 65 + tk * 4 + 0] = m;
    kbuf[row * 65 + tk * 4 + 1] = s;
    kbuf[row * 65 + tk * 4 + 2] = t;
    kbuf[row * 65 + tk * 4 + 3] = (float)bi;
  }
  __syncthreads();
  if (tid < RT) {
    int r = tid;
    float M = -INFINITY, S = 0.f, T = 0.f, BM = -INFINITY;
    int BI = 0x7fffffff;
    for (int j = 0; j < 16; ++j) {
      float m  = kbuf[r * 65 + j * 4 + 0];
      float s  = kbuf[r * 65 + j * 4 + 1];
      float t  = kbuf[r * 65 + j * 4 + 2];
      int   bi = (int)kbuf[r * 65 + j * 4 + 3];
      if (m <= M) {
        float e = expf(m - M);
        S += s * e; T += t * e;
      } else {
        float e = expf(M - m);
        S = S * e + s; T = T * e + t; M = m;
      }
      if (m > BM || (m == BM && bi < BI)) { BM = m; BI = bi; }
    }
    float kl = logf((float)N_CODES) + T / S - M - logf(S);
    atomicAdd(&ws_acc[0], kl);
    out[OUT_CODE + (size_t)(r0 + r)] = (float)BI;
  }
  float cpart = 0.f;
#pragma unroll
  for (int j = 0; j < 8; ++j) {
    int row  = rowg * 8 + j;
    int grow = r0 + row;
    float inv = 1.0f / s2s[row];
    float4 zv = *(const float4*)(&zt[row * ZSTRIDE + d4]);
    float q0 = acc2[j][0] * inv, q1 = acc2[j][1] * inv;
    float q2 = acc2[j][2] * inv, q3 = acc2[j][3] * inv;
    float e0 = q0 - zv.x, e1 = q1 - zv.y, e2 = q2 - zv.z, e3 = q3 - zv.w;
    cpart += e0*e0 + e1*e1 + e2*e2 + e3*e3;
    float4 o;
    o.x = zv.x + e0; o.y = zv.y + e1; o.z = zv.z + e2; o.w = zv.w + e3;
    *(float4*)(&out[(size_t)grow * DIMV + d4]) = o;
  }
#pragma unroll
  for (int off = 32; off > 0; off >>= 1) cpart += __shfl_down(cpart, off, 64);
  __syncthreads();
  if ((tid & 63) == 0) redb[tid >> 6] = cpart;
  __syncthreads();
  if (tid == 0) {
    float cs = redb[0] + redb[1] + redb[2] + redb[3];
    atomicAdd(&ws_acc[1], cs);
  }
}

__global__ void vq_finalize(const float* __restrict__ ws_acc, float* __restrict__ out) {
  if (threadIdx.x == 0 && blockIdx.x == 0) {
    float kl = 0.01f * (ws_acc[0] / (float)N_ROWS);
    float cm = 0.25f * (ws_acc[1] / (float)OUT_ZQ_N);
    out[OUT_LOSS] = cm + kl;
  }
}

extern "C" void kernel_launch(void* const* d_in, const int* in_sizes, int n_in,
                              void* d_out, int out_size, void* d_ws, size_t ws_size,
                              hipStream_t stream) {
  (void)in_sizes; (void)n_in; (void)out_size;
  const float* z  = (const float*)d_in[0];
  const float* cb = (const float*)d_in[1];
  float* out = (float*)d_out;
  if (ws_size >= (size_t)WS_NEED) {
    char* ws = (char*)d_ws;
    hipMemsetAsync(ws + WS_ACC, 0, 8, stream);
    vq_prep<<<256, 256, 0, stream>>>(cb, ws);
    vq_main_v2<<<N_ROWS / RT, 256, 0, stream>>>(z, cb, out, ws);
    vq_finalize<<<1, 64, 0, stream>>>((const float*)(ws + WS_ACC), out);
  } else {
    float* ws = (float*)d_ws;
    hipMemsetAsync(ws, 0, 8, stream);
    vq_main_v1<<<N_ROWS / RT, 256, 0, stream>>>(z, cb, out, ws);
    vq_finalize<<<1, 64, 0, stream>>>(ws, out);
  }
}

// Round 6
// 711.203 us; speedup vs baseline: 1.2668x; 1.1727x over previous
//
#include <hip/hip_runtime.h>
#include <stdint.h>
#include <math.h>

// ---------------- problem constants ----------------
#define N_ROWS   16384
#define N_CODES  8192
#define DIMV     256
#define RT       32
#define CK       32
#define NCHUNK   (N_CODES / CK)
#define OUT_ZQ_N ((size_t)N_ROWS * DIMV)
#define OUT_LOSS OUT_ZQ_N
#define OUT_CODE (OUT_ZQ_N + 1)

// ---------------- workspace layout ----------------
#define WS_CBHI 0u
#define WS_CBT  4194304u
#define WS_ACC  8388608u
#define WS_NEED (8388608u + 64u)

// ---------------- LDS layout (bytes) ----------------
// All DMA destination blocks are 1024B data at 1056B stride: adjacent blocks
// staggered by 8 banks so concurrent global_load_lds streams don't collide on
// the LDS write port (R3 evidence: 1056 -> 5.0e7 conflicts, 1024 -> 1.1e8).
#define CB1H_OFF  0        // 16 blocks (2 codes x 512B each)
#define CBT0_OFF  16896
#define CBT1_OFF  33792
#define BSTRIDE   1056
#define P_OFF     50688    // [32 rows][40 ushort] bf16 hi-only
#define P_ROW     80
#define S2B_OFF   53248    // [2][32] f32
#define SKL_OFF   53504
#define TKL_OFF   53760
#define SMEM_BYTES 54016
#define ZT_ROWF   260      // epilogue z fp32 tile stride (floats), overlays 0..33280
#define CAND_OFF  33792    // epilogue candidate dump overlays CBT1 (32 rows x 64 x 8B)

typedef __attribute__((ext_vector_type(8))) short short8;
typedef __attribute__((ext_vector_type(4))) float float4v;

typedef __attribute__((address_space(1))) uint32_t g_u32;
typedef __attribute__((address_space(3))) uint32_t l_u32;

// async global->LDS DMA, 16B/lane; LDS dest = wave-uniform base + lane*16
__device__ __forceinline__ void dma16(const void* gsrc, void* ldst) {
  __builtin_amdgcn_global_load_lds((g_u32*)gsrc, (l_u32*)ldst, 16, 0, 0);
}

__device__ __forceinline__ uint32_t rotl32(uint32_t x, int r) {
  return __builtin_rotateleft32(x, (uint32_t)r);
}

// Threefry-2x32, key=(0,42), counter=(0, c); out0^out1 (JAX partitionable).
__device__ __forceinline__ uint32_t threefry_bits(uint32_t c) {
  const uint32_t k0 = 0u, k1 = 42u;
  const uint32_t k2 = 0x1BD11BDAu ^ k0 ^ k1;
  uint32_t x0 = 0u + k0;
  uint32_t x1 = c + k1;
#define TF_R(r) { x0 += x1; x1 = rotl32(x1, r); x1 ^= x0; }
  TF_R(13) TF_R(15) TF_R(26) TF_R(6)
  x0 += k1; x1 += k2 + 1u;
  TF_R(17) TF_R(29) TF_R(16) TF_R(24)
  x0 += k2; x1 += k0 + 2u;
  TF_R(13) TF_R(15) TF_R(26) TF_R(6)
  x0 += k0; x1 += k1 + 3u;
  TF_R(17) TF_R(29) TF_R(16) TF_R(24)
  x0 += k1; x1 += k2 + 4u;
  TF_R(13) TF_R(15) TF_R(26) TF_R(6)
  x0 += k2; x1 += k0 + 5u;
#undef TF_R
  return x0 ^ x1;
}

// accurate gumbel for the v1 fallback path
__device__ __forceinline__ float gumbel_at_v1(uint32_t idx) {
  uint32_t bits = threefry_bits(idx);
  float u = __uint_as_float((bits >> 9) | 0x3f800000u) - 1.0f;
  u = fmaxf(u, 1.17549435e-38f);
  return -logf(-logf(u));
}

__device__ __forceinline__ unsigned short f2bf(float x) {
  uint32_t u = __float_as_uint(x);
  u += 0x7fffu + ((u >> 16) & 1u);
  return (unsigned short)(u >> 16);
}
__device__ __forceinline__ float bf2f(unsigned short h) {
  return __uint_as_float(((uint32_t)h) << 16);
}

// ================= prep: cb fp32 -> bf16 hi + chunk-blocked transpose =================
__global__ __launch_bounds__(256)
void vq_prep(const float* __restrict__ cb, char* __restrict__ ws) {
  __shared__ unsigned short lhs[32 * 260];
  const int c = blockIdx.x;
  const int tid = threadIdx.x;
  const int k0 = c * 32;
  unsigned short* cbhi = (unsigned short*)(ws + WS_CBHI);
  unsigned short* cbt  = (unsigned short*)(ws + WS_CBT);
#pragma unroll
  for (int i = 0; i < 8; ++i) {
    int F = tid + i * 256;
    int code = F >> 6, d4 = (F & 63) * 4;
    float4 v = *(const float4*)(cb + (size_t)(k0 + code) * DIMV + d4);
    unsigned short h0 = f2bf(v.x), h1 = f2bf(v.y), h2 = f2bf(v.z), h3 = f2bf(v.w);
    ushort4 hv = {h0, h1, h2, h3};
    *(ushort4*)(cbhi + (size_t)(k0 + code) * DIMV + d4) = hv;
    *(ushort4*)(&lhs[code * 260 + d4]) = hv;
  }
  __syncthreads();
  const int d = tid;
  unsigned short vals[32];
#pragma unroll
  for (int cc = 0; cc < 32; ++cc) vals[cc] = lhs[cc * 260 + d];
  unsigned short* base = cbt + (size_t)c * 8192 + (size_t)d * 32;
#pragma unroll
  for (int j = 0; j < 8; ++j) {
    ushort4 w = {vals[4 * j], vals[4 * j + 1], vals[4 * j + 2], vals[4 * j + 3]};
    *(ushort4*)(base + j * 4) = w;
  }
}

// ================= main v6: hh-only GEMM1, top-8 fp64 code refine =================
__global__ __launch_bounds__(256, 2)
void vq_main_v2(const float* __restrict__ z, const float* __restrict__ cb,
                float* __restrict__ out, char* __restrict__ ws) {
  __shared__ __align__(16) char sm[SMEM_BYTES];
  const int tid  = threadIdx.x;
  const int wave = tid >> 6;
  const int lane = tid & 63;
  const int quad = lane >> 4;
  const int n    = lane & 15;
  const int mt   = wave & 1;
  const int nt   = wave >> 1;
  const int r0   = blockIdx.x * RT;
  const int myrow = mt * 16 + quad * 4;      // C-layout base row
  const char* cbhi_b = ws + WS_CBHI;
  const char* cbt_b  = ws + WS_CBT;
  float* wsA = (float*)(ws + WS_ACC);

  // ---- prologue: stage z fp32 tile, build A-fragments (hi only) ----
  {
    float* zts = (float*)sm;
#pragma unroll
    for (int i = 0; i < 8; ++i) {
      int F = tid + i * 256;
      int row = F >> 6, d4 = (F & 63) * 4;
      *(float4*)(zts + row * ZT_ROWF + d4) =
          *(const float4*)(z + (size_t)(r0 + row) * DIMV + d4);
    }
  }
  __syncthreads();
  short8 zhi[8];
  {
    const float* zts = (const float*)sm;
    const int rowl = mt * 16 + n;            // A-frag m = lane&15
#pragma unroll
    for (int ks = 0; ks < 8; ++ks) {
      const float* zp = zts + rowl * ZT_ROWF + ks * 32 + quad * 8;
      float4 f0 = *(const float4*)zp;
      float4 f1 = *(const float4*)(zp + 4);
      zhi[ks][0] = (short)f2bf(f0.x); zhi[ks][1] = (short)f2bf(f0.y);
      zhi[ks][2] = (short)f2bf(f0.z); zhi[ks][3] = (short)f2bf(f0.w);
      zhi[ks][4] = (short)f2bf(f1.x); zhi[ks][5] = (short)f2bf(f1.y);
      zhi[ks][6] = (short)f2bf(f1.z); zhi[ks][7] = (short)f2bf(f1.w);
    }
  }
  __syncthreads();   // all waves done reading z-tile (CB1 region reuse)

  // ---- prologue staging: CB1(0) + CBT(0) -> buf0 ----
#pragma unroll
  for (int i = 0; i < 4; ++i) {
    int b = wave * 4 + i;
    dma16(cbhi_b + (size_t)(2 * b) * 512 + (size_t)lane * 16, sm + CB1H_OFF + b * BSTRIDE);
    dma16(cbt_b + (size_t)b * 1024 + (size_t)lane * 16, sm + CBT0_OFF + b * BSTRIDE);
  }

  // ---- per-lane persistent state ----
  float skl[4] = {0.f, 0.f, 0.f, 0.f};
  float tkl[4] = {0.f, 0.f, 0.f, 0.f};
  float s2l[4] = {0.f, 0.f, 0.f, 0.f};
  float v1[4], v2[4];
  int   i1[4], i2[4];
  uint32_t idxr[4];
#pragma unroll
  for (int r = 0; r < 4; ++r) {
    v1[r] = -INFINITY; v2[r] = -INFINITY;
    i1[r] = 0x7fffffff; i2[r] = 0x7fffffff;
    idxr[r] = (uint32_t)(r0 + myrow + r) * (uint32_t)N_CODES + (uint32_t)(nt * 16 + n);
  }
  float4v acc2[8];
#pragma unroll
  for (int t = 0; t < 8; ++t) acc2[t] = (float4v){0.f, 0.f, 0.f, 0.f};

  const int kc = nt * 16 + n;
  const char* bbase = sm + CB1H_OFF + (kc >> 1) * BSTRIDE + (kc & 1) * 512 + quad * 16;

  for (int c = 0; c < NCHUNK; ++c) {
    __syncthreads();   // S0: drains CB1(c) DMA (behind GEMM2(c-1)); CBT alt buf free

    // stage CBT(c+1) -> alt buffer; drains at S4 behind GEMM1+phaseC (hidden)
    if (c + 1 < NCHUNK) {
#pragma unroll
      for (int i = 0; i < 4; ++i) {
        int b = wave * 4 + i;
        dma16(cbt_b + (size_t)(c + 1) * 16384 + (size_t)b * 1024 + (size_t)lane * 16,
              sm + (((c + 1) & 1) ? CBT1_OFF : CBT0_OFF) + b * BSTRIDE);
      }
    }

    // ---- GEMM1: logits, hh term only, 2 independent chains ----
    float4v e0 = (float4v){0.f, 0.f, 0.f, 0.f};
    float4v e1 = (float4v){0.f, 0.f, 0.f, 0.f};
#pragma unroll
    for (int ks = 0; ks < 4; ++ks) {
      short8 ba = *(const short8*)(bbase + (2 * ks) * 64);
      short8 bb = *(const short8*)(bbase + (2 * ks + 1) * 64);
      e0 = __builtin_amdgcn_mfma_f32_16x16x32_bf16(zhi[2 * ks], ba, e0, 0, 0, 0);
      e1 = __builtin_amdgcn_mfma_f32_16x16x32_bf16(zhi[2 * ks + 1], bb, e1, 0, 0, 0);
    }
    float4v acc1 = e0 + e1;

    // ---- phase C: threefry, KL stats, top2, P-hi write ----
    const int codeg0 = c * CK + kc;
#pragma unroll
    for (int r = 0; r < 4; ++r) {
      float l = acc1[r];
      uint32_t bits = threefry_bits(idxr[r]);
      idxr[r] += 32u;
      float u = __uint_as_float((bits >> 9) | 0x3f800000u) - 1.0f;   // [0,1)
      float h = u - 1.0f;
      float uu = fmaxf(u, 1.17549435e-38f);
      float t_hw = -0.69314718056f * __log2f(uu);
      float poly = 1.0f + h * (-0.5f + h * (0.33333333f + h * (-0.25f)));
      float t = (h > -0.015625f) ? (-h * poly) : t_hw;
      float e = __expf(l);
      skl[r] += e;
      tkl[r] = fmaf(e, l, tkl[r]);
      bool b1 = l > v1[r];
      bool b2 = l > v2[r];
      v2[r] = b1 ? v1[r] : (b2 ? l : v2[r]);
      i2[r] = b1 ? i1[r] : (b2 ? codeg0 : i2[r]);
      v1[r] = b1 ? l : v1[r];
      i1[r] = b1 ? codeg0 : i1[r];
      // exp(l + g - 12) == exp(l)/t * e^-12 ; P stored hi-only bf16
      float p = e * __builtin_amdgcn_rcpf(t) * 6.1442123533282097e-06f;
      unsigned short ph = f2bf(p);
      s2l[r] += bf2f(ph);                  // denominator from rounded P
      *(unsigned short*)(sm + P_OFF + (myrow + r) * P_ROW + kc * 2) = ph;
    }
    __syncthreads();   // S4: P ready; CBT(c+1) arrived (hidden drain)

    // stage CB1(c+1); drains at S0(c+1) behind GEMM2
    if (c + 1 < NCHUNK) {
      const size_t k1 = (size_t)(c + 1) * CK;
#pragma unroll
      for (int i = 0; i < 4; ++i) {
        int b = wave * 4 + i;
        dma16(cbhi_b + (k1 + 2 * b) * 512 + (size_t)lane * 16, sm + CB1H_OFF + b * BSTRIDE);
      }
    }

    // ---- GEMM2: z_q += P_hi * CBT[c&1] ----
    {
      const char* cbtb = sm + ((c & 1) ? CBT1_OFF : CBT0_OFF);
      short8 pah0 = *(const short8*)(sm + P_OFF + n * P_ROW + quad * 16);
      short8 pah1 = *(const short8*)(sm + P_OFF + (16 + n) * P_ROW + quad * 16);
#pragma unroll
      for (int t = 0; t < 4; ++t) {
        int dt = wave * 4 + t;               // dims dt*16 .. dt*16+15
        short8 bb = *(const short8*)(cbtb + dt * BSTRIDE + n * 64 + quad * 16);
        acc2[t * 2 + 0] = __builtin_amdgcn_mfma_f32_16x16x32_bf16(pah0, bb, acc2[t * 2 + 0], 0, 0, 0);
        acc2[t * 2 + 1] = __builtin_amdgcn_mfma_f32_16x16x32_bf16(pah1, bb, acc2[t * 2 + 1], 0, 0, 0);
      }
    }
  }

  // ================= epilogue =================
  // reduce scalar stats over the 16-lane n-group (registers only)
#pragma unroll
  for (int m = 1; m <= 8; m <<= 1) {
#pragma unroll
    for (int r = 0; r < 4; ++r) {
      s2l[r] += __shfl_xor(s2l[r], m);
      skl[r] += __shfl_xor(skl[r], m);
      tkl[r] += __shfl_xor(tkl[r], m);
    }
  }
  if (n == 0) {
    int off = (nt * 32 + myrow) * 4;
    float4 fs = {s2l[0], s2l[1], s2l[2], s2l[3]};
    *(float4*)(sm + S2B_OFF + off) = fs;
    float4 fk = {skl[0], skl[1], skl[2], skl[3]};
    *(float4*)(sm + SKL_OFF + off) = fk;
    float4 ft = {tkl[0], tkl[1], tkl[2], tkl[3]};
    *(float4*)(sm + TKL_OFF + off) = ft;
  }
  // restage z fp32 tile over CB1H+CBT0 (safe: CB1H last read pre-S4(255),
  // CBT0 last read at GEMM2(254) pre-S0(255))
  {
    float* zts = (float*)sm;
#pragma unroll
    for (int i = 0; i < 8; ++i) {
      int F = tid + i * 256;
      int row = F >> 6, d4 = (F & 63) * 4;
      *(float4*)(zts + row * ZT_ROWF + d4) =
          *(const float4*)(z + (size_t)(r0 + row) * DIMV + d4);
    }
  }
  __syncthreads();                           // E1: GEMM2(255) CBT1 reads done

  // dump per-lane top-2 candidates: cand[row][nt*32 + n*2 + rank] = (v, idx)
#pragma unroll
  for (int r = 0; r < 4; ++r) {
    char* cbase = sm + CAND_OFF + (myrow + r) * 512 + (nt * 32 + n * 2) * 8;
    *(float*)(cbase + 0) = v1[r];
    *(int*)(cbase + 4)   = i1[r];
    *(float*)(cbase + 8) = v2[r];
    *(int*)(cbase + 12)  = i2[r];
  }
  __syncthreads();                           // E2

  const float* zts = (const float*)sm;

  // KL per row (one lane per row)
  if (tid < 32) {
    int r = tid;
    const float* sklb = (const float*)(sm + SKL_OFF);
    const float* tklb = (const float*)(sm + TKL_OFF);
    float S = sklb[r] + sklb[32 + r];
    float T = tklb[r] + tklb[32 + r];
    float klr = T / S - __logf(S) + 9.010913347279288f;   // ln(8192)
#pragma unroll
    for (int m = 1; m <= 16; m <<= 1) klr += __shfl_xor(klr, m);
    if (r == 0) atomicAdd(&wsA[0], klr);
  }

  // codes: top-8 by noisy logit, fp64 refine; 2 lanes per row
  if (tid < 64) {
    int r = tid >> 1, h = tid & 1;
    const char* cbase = sm + CAND_OFF + r * 512 + h * 256;   // 32 entries x 8B
    float bv[8]; int bi8[8];
#pragma unroll
    for (int k = 0; k < 8; ++k) { bv[k] = -INFINITY; bi8[k] = 0x7fffffff; }
    for (int s = 0; s < 32; ++s) {
      float v = *(const float*)(cbase + s * 8);
      int  id = *(const int*)(cbase + s * 8 + 4);
      if ((v > bv[7]) || (v == bv[7] && id < bi8[7])) {
        float cv = v; int ci = id;
#pragma unroll
        for (int k = 0; k < 8; ++k) {
          bool sw = (cv > bv[k]) || (cv == bv[k] && ci < bi8[k]);
          float tv = bv[k]; int ti = bi8[k];
          if (sw) { bv[k] = cv; bi8[k] = ci; cv = tv; ci = ti; }
        }
      }
    }
    // merge partner half's top-8
    float ovv[8]; int ovi[8];
#pragma unroll
    for (int k = 0; k < 8; ++k) {
      ovv[k] = __shfl_xor(bv[k], 1);
      ovi[k] = __shfl_xor(bi8[k], 1);
    }
#pragma unroll
    for (int kk = 0; kk < 8; ++kk) {
      float cv = ovv[kk]; int ci = ovi[kk];
      if ((cv > bv[7]) || (cv == bv[7] && ci < bi8[7])) {
#pragma unroll
        for (int k = 0; k < 8; ++k) {
          bool sw = (cv > bv[k]) || (cv == bv[k] && ci < bi8[k]);
          float tv = bv[k]; int ti = bi8[k];
          if (sw) { bv[k] = cv; bi8[k] = ci; cv = tv; ci = ti; }
        }
      }
    }
    // fp64 refine 4 candidates per lane (lane h takes entries h*4..h*4+3)
    const float* zp = zts + r * ZT_ROWF;
    double best = -1.0e300;
    int bidx = 0x7fffffff;
#pragma unroll
    for (int k = 0; k < 4; ++k) {
      int cidx = bi8[h * 4 + k];
      const float* cp = cb + (size_t)cidx * DIMV;
      double d = 0.0;
      for (int dd = 0; dd < DIMV; dd += 4) {
        float4 zv = *(const float4*)(zp + dd);
        float4 xv = *(const float4*)(cp + dd);
        d += (double)zv.x * xv.x + (double)zv.y * xv.y +
             (double)zv.z * xv.z + (double)zv.w * xv.w;
      }
      if (d > best || (d == best && cidx < bidx)) { best = d; bidx = cidx; }
    }
    double obest = __shfl_xor(best, 1);
    int    obidx = __shfl_xor(bidx, 1);
    bool take = (obest > best) || (obest == best && obidx < bidx);
    int finali = take ? obidx : bidx;
    if (h == 0) out[OUT_CODE + (size_t)(r0 + r)] = (float)finali;
  }

  // z_q_st + commit partial
  float invm0[4], invm1[4];
  {
    const float* s2b = (const float*)(sm + S2B_OFF);
#pragma unroll
    for (int e = 0; e < 4; ++e) {
      float Sa = s2b[quad * 4 + e] + s2b[32 + quad * 4 + e];
      float Sb = s2b[16 + quad * 4 + e] + s2b[32 + 16 + quad * 4 + e];
      invm0[e] = 1.0f / Sa;
      invm1[e] = 1.0f / Sb;
    }
  }
  float cpart = 0.f;
#pragma unroll
  for (int t = 0; t < 4; ++t) {
    int dim = (wave * 4 + t) * 16 + n;
#pragma unroll
    for (int ms = 0; ms < 2; ++ms) {
      float4v a = acc2[t * 2 + ms];
#pragma unroll
      for (int e = 0; e < 4; ++e) {
        int row = ms * 16 + quad * 4 + e;
        float q = a[e] * (ms ? invm1[e] : invm0[e]);
        float zv = zts[row * ZT_ROWF + dim];
        float err = q - zv;
        cpart += err * err;
        out[(size_t)(r0 + row) * DIMV + dim] = zv + err;
      }
    }
  }
#pragma unroll
  for (int m = 1; m <= 32; m <<= 1) cpart += __shfl_xor(cpart, m);
  if (lane == 0) atomicAdd(&wsA[1], cpart);
}

// ================= fallback v1 (fp32 VALU, needs only 8B ws) =================
#define ZSTRIDE  260
#define CSTRIDE  260
#define PSTRIDE  36
#define RSTRIDE  17

__global__ __launch_bounds__(256, 2)
void vq_main_v1(const float* __restrict__ z, const float* __restrict__ cb,
                float* __restrict__ out, float* __restrict__ ws_acc) {
  __shared__ float zt[RT * ZSTRIDE];
  __shared__ float cbt[CK * CSTRIDE];
  __shared__ float ptile[RT * PSTRIDE];
  __shared__ float redb[RT * RSTRIDE];
  __shared__ float m2s[RT], s2s[RT], scls[RT];

  const int tid = threadIdx.x;
  const int r0  = blockIdx.x * RT;
#pragma unroll
  for (int p = 0; p < 8; ++p) {
    int q = tid + p * 256;
    int i = q >> 6, c4 = (q & 63) * 4;
    *(float4*)(&zt[i * ZSTRIDE + c4]) = *(const float4*)(z + (size_t)(r0 + i) * DIMV + c4);
  }
  if (tid < RT) { m2s[tid] = -INFINITY; s2s[tid] = 0.f; scls[tid] = 0.f; }
  const int tr = tid & 15, tk = tid >> 4, rowg = tid >> 6;
  const int d4 = (tid & 63) * 4;
  float c_m[2][2], c_s[2][2], c_t[2][2];
  int   c_i[2][2];
#pragma unroll
  for (int a = 0; a < 2; ++a)
#pragma unroll
    for (int b = 0; b < 2; ++b) { c_m[a][b] = -INFINITY; c_s[a][b] = 0.f; c_t[a][b] = 0.f; c_i[a][b] = 0; }
  float acc2[8][4];
#pragma unroll
  for (int j = 0; j < 8; ++j)
#pragma unroll
    for (int e = 0; e < 4; ++e) acc2[j][e] = 0.f;
  __syncthreads();
  for (int c = 0; c < NCHUNK; ++c) {
    const int k0 = c * CK;
#pragma unroll
    for (int p = 0; p < 8; ++p) {
      int q = tid + p * 256;
      int i = q >> 6, c4 = (q & 63) * 4;
      *(float4*)(&cbt[i * CSTRIDE + c4]) = *(const float4*)(cb + (size_t)(k0 + i) * DIMV + c4);
    }
    __syncthreads();
    float l00 = 0.f, l01 = 0.f, l10 = 0.f, l11 = 0.f;
    {
      const float* zp0 = &zt[tr * ZSTRIDE];
      const float* zp1 = &zt[(tr + 16) * ZSTRIDE];
      const float* bp0 = &cbt[tk * CSTRIDE];
      const float* bp1 = &cbt[(tk + 16) * CSTRIDE];
#pragma unroll 4
      for (int d = 0; d < DIMV; d += 4) {
        float4 a0 = *(const float4*)(zp0 + d);
        float4 a1 = *(const float4*)(zp1 + d);
        float4 b0 = *(const float4*)(bp0 + d);
        float4 b1 = *(const float4*)(bp1 + d);
        l00 += a0.x*b0.x + a0.y*b0.y + a0.z*b0.z + a0.w*b0.w;
        l01 += a0.x*b1.x + a0.y*b1.y + a0.z*b1.z + a0.w*b1.w;
        l10 += a1.x*b0.x + a1.y*b0.y + a1.z*b0.z + a1.w*b0.w;
        l11 += a1.x*b1.x + a1.y*b1.y + a1.z*b1.z + a1.w*b1.w;
      }
    }
    float lv2[2][2] = {{l00, l01}, {l10, l11}};
    float a2[2][2];
#pragma unroll
    for (int a = 0; a < 2; ++a) {
      int grow = r0 + tr + a * 16;
#pragma unroll
      for (int b = 0; b < 2; ++b) {
        int gk = k0 + tk + b * 16;
        float g  = gumbel_at_v1((uint32_t)grow * (uint32_t)N_CODES + (uint32_t)gk);
        float lv = lv2[a][b];
        a2[a][b] = lv + g;
        if (lv > c_m[a][b]) {
          float sc = expf(c_m[a][b] - lv);
          c_s[a][b] = c_s[a][b] * sc + 1.0f;
          c_t[a][b] = c_t[a][b] * sc + lv;
          c_m[a][b] = lv;
          c_i[a][b] = gk;
        } else {
          float e = expf(lv - c_m[a][b]);
          c_s[a][b] += e;
          c_t[a][b] += e * lv;
        }
      }
    }
    redb[tr * RSTRIDE + tk]        = fmaxf(a2[0][0], a2[0][1]);
    redb[(tr + 16) * RSTRIDE + tk] = fmaxf(a2[1][0], a2[1][1]);
    __syncthreads();
    if (tid < RT) {
      float cm = -INFINITY;
#pragma unroll
      for (int j = 0; j < 16; ++j) cm = fmaxf(cm, redb[tid * RSTRIDE + j]);
      float m2n = fmaxf(m2s[tid], cm);
      scls[tid] = expf(m2s[tid] - m2n);
      m2s[tid]  = m2n;
    }
    __syncthreads();
#pragma unroll
    for (int a = 0; a < 2; ++a) {
      int row = tr + a * 16;
      float m2r = m2s[row];
      float p0 = expf(a2[a][0] - m2r);
      float p1 = expf(a2[a][1] - m2r);
      ptile[row * PSTRIDE + tk]      = p0;
      ptile[row * PSTRIDE + tk + 16] = p1;
      redb[row * RSTRIDE + tk] = p0 + p1;
    }
    __syncthreads();
    if (tid < RT) {
      float ss = 0.f;
#pragma unroll
      for (int j = 0; j < 16; ++j) ss += redb[tid * RSTRIDE + j];
      s2s[tid] = s2s[tid] * scls[tid] + ss;
    }
#pragma unroll
    for (int j = 0; j < 8; ++j) {
      float sc = scls[rowg * 8 + j];
      acc2[j][0] *= sc; acc2[j][1] *= sc; acc2[j][2] *= sc; acc2[j][3] *= sc;
    }
    for (int k4 = 0; k4 < CK; k4 += 4) {
      float4 cb0 = *(const float4*)(&cbt[(k4 + 0) * CSTRIDE + d4]);
      float4 cb1v = *(const float4*)(&cbt[(k4 + 1) * CSTRIDE + d4]);
      float4 cb2 = *(const float4*)(&cbt[(k4 + 2) * CSTRIDE + d4]);
      float4 cb3 = *(const float4*)(&cbt[(k4 + 3) * CSTRIDE + d4]);
#pragma unroll
      for (int j = 0; j < 8; ++j) {
        float4 p4 = *(const float4*)(&ptile[(rowg * 8 + j) * PSTRIDE + k4]);
        acc2[j][0] += p4.x*cb0.x + p4.y*cb1v.x + p4.z*cb2.x + p4.w*cb3.x;
        acc2[j][1] += p4.x*cb0.y + p4.y*cb1v.y + p4.z*cb2.y + p4.w*cb3.y;
        acc2[j][2] += p4.x*cb0.z + p4.y*cb1v.z + p4.z*cb2.z + p4.w*cb3.z;
        acc2[j][3] += p4.x*cb0.w + p4.y*cb1v.w + p4.z*cb2.w + p4.w*cb3.w;
      }
    }
    __syncthreads();
  }
  float* kbuf = cbt;
#pragma unroll
  for (int a = 0; a < 2; ++a) {
    float m0 = c_m[a][0], m1v = c_m[a][1];
    float m, s, t; int bi;
    if (m0 >= m1v) {
      float e = expf(m1v - m0);
      m = m0; s = c_s[a][0] + c_s[a][1] * e; t = c_t[a][0] + c_t[a][1] * e;
    } else {
      float e = expf(m0 - m1v);
      m = m1v; s = c_s[a][0] * e + c_s[a][1]; t = c_t[a][0] * e + c_t[a][1];
    }
    if (m0 > m1v)      bi = c_i[a][0];
    else if (m1v > m0) bi = c_i[a][1];
    else               bi = min(c_i[a][0], c_i[a][1]);
    int row = tr + a * 16;
    kbuf[row * 65 + tk * 4 + 0] = m;
    kbuf[row * 65 + tk * 4 + 1] = s;
    kbuf[row * 65 + tk * 4 + 2] = t;
    kbuf[row * 65 + tk * 4 + 3] = (float)bi;
  }
  __syncthreads();
  if (tid < RT) {
    int r = tid;
    float M = -INFINITY, S = 0.f, T = 0.f, BM = -INFINITY;
    int BI = 0x7fffffff;
    for (int j = 0; j < 16; ++j) {
      float m  = kbuf[r * 65 + j * 4 + 0];
      float s  = kbuf[r * 65 + j * 4 + 1];
      float t  = kbuf[r * 65 + j * 4 + 2];
      int   bi = (int)kbuf[r * 65 + j * 4 + 3];
      if (m <= M) {
        float e = expf(m - M);
        S += s * e; T += t * e;
      } else {
        float e = expf(M - m);
        S = S * e + s; T = T * e + t; M = m;
      }
      if (m > BM || (m == BM && bi < BI)) { BM = m; BI = bi; }
    }
    float kl = logf((float)N_CODES) + T / S - M - logf(S);
    atomicAdd(&ws_acc[0], kl);
    out[OUT_CODE + (size_t)(r0 + r)] = (float)BI;
  }
  float cpart = 0.f;
#pragma unroll
  for (int j = 0; j < 8; ++j) {
    int row  = rowg * 8 + j;
    int grow = r0 + row;
    float inv = 1.0f / s2s[row];
    float4 zv = *(const float4*)(&zt[row * ZSTRIDE + d4]);
    float q0 = acc2[j][0] * inv, q1 = acc2[j][1] * inv;
    float q2 = acc2[j][2] * inv, q3 = acc2[j][3] * inv;
    float e0 = q0 - zv.x, e1 = q1 - zv.y, e2 = q2 - zv.z, e3 = q3 - zv.w;
    cpart += e0*e0 + e1*e1 + e2*e2 + e3*e3;
    float4 o;
    o.x = zv.x + e0; o.y = zv.y + e1; o.z = zv.z + e2; o.w = zv.w + e3;
    *(float4*)(&out[(size_t)grow * DIMV + d4]) = o;
  }
#pragma unroll
  for (int off = 32; off > 0; off >>= 1) cpart += __shfl_down(cpart, off, 64);
  __syncthreads();
  if ((tid & 63) == 0) redb[tid >> 6] = cpart;
  __syncthreads();
  if (tid == 0) {
    float cs = redb[0] + redb[1] + redb[2] + redb[3];
    atomicAdd(&ws_acc[1], cs);
  }
}

__global__ void vq_finalize(const float* __restrict__ ws_acc, float* __restrict__ out) {
  if (threadIdx.x == 0 && blockIdx.x == 0) {
    float kl = 0.01f * (ws_acc[0] / (float)N_ROWS);
    float cm = 0.25f * (ws_acc[1] / (float)OUT_ZQ_N);
    out[OUT_LOSS] = cm + kl;
  }
}

extern "C" void kernel_launch(void* const* d_in, const int* in_sizes, int n_in,
                              void* d_out, int out_size, void* d_ws, size_t ws_size,
                              hipStream_t stream) {
  (void)in_sizes; (void)n_in; (void)out_size;
  const float* z  = (const float*)d_in[0];
  const float* cb = (const float*)d_in[1];
  float* out = (float*)d_out;
  if (ws_size >= (size_t)WS_NEED) {
    char* ws = (char*)d_ws;
    hipMemsetAsync(ws + WS_ACC, 0, 8, stream);
    vq_prep<<<256, 256, 0, stream>>>(cb, ws);
    vq_main_v2<<<N_ROWS / RT, 256, 0, stream>>>(z, cb, out, ws);
    vq_finalize<<<1, 64, 0, stream>>>((const float*)(ws + WS_ACC), out);
  } else {
    float* ws = (float*)d_ws;
    hipMemsetAsync(ws, 0, 8, stream);
    vq_main_v1<<<N_ROWS / RT, 256, 0, stream>>>(z, cb, out, ws);
    vq_finalize<<<1, 64, 0, stream>>>(ws, out);
  }
}

// Round 7
// 706.805 us; speedup vs baseline: 1.2747x; 1.0062x over previous
//
#include <hip/hip_runtime.h>
#include <stdint.h>
#include <math.h>

// ---------------- problem constants ----------------
#define N_ROWS   16384
#define N_CODES  8192
#define DIMV     256
#define RT       32
#define CK       32
#define NCHUNK   (N_CODES / CK)
#define OUT_ZQ_N ((size_t)N_ROWS * DIMV)
#define OUT_LOSS OUT_ZQ_N
#define OUT_CODE (OUT_ZQ_N + 1)

// ---------------- workspace layout ----------------
#define WS_CBHI 0u
#define WS_CBT  4194304u
#define WS_ACC  8388608u
#define WS_NEED (8388608u + 64u)

// ---------------- LDS layout (bytes) ----------------
// 36.3 KB total -> 4 blocks/CU (16 waves/CU). DMA blocks: 1024B data at
// 1056B stride (8-bank stagger between concurrent global_load_lds streams;
// measured: 1056 -> 3.0e7 conflicts, 1024/1040 -> 1.1e8).
// Schedule: CBT(c) issued at S0(c), drains at S4(c) behind GEMM1+phaseC
// (~800+ cyc >> DMA latency -> hidden). CB1H(c+1) issued after S4(c),
// drains at S0(c+1) behind GEMM2 (~200 cyc exposed).
#define CB1H_OFF  0        // 16 blocks (2 codes x 512B each)
#define CBT_OFF   16896    // 16 blocks (16 dims x 64B each)
#define BSTRIDE   1056
#define P_OFF     33792    // [32 rows][40 ushort] bf16 hi-only
#define P_ROW     80
#define S2B_OFF   36352    // [2][32] f32
#define SKL_OFF   36608
#define TKL_OFF   36864
#define SMEM_BYTES 37120
#define ZT_ROWF   260      // prologue z fp32 tile stride (floats), overlays 0..33280
#define CAND_OFF  0        // epilogue candidate dump overlays CB1H (32 rows x 64 x 8B = 16KB)

typedef __attribute__((ext_vector_type(8))) short short8;
typedef __attribute__((ext_vector_type(4))) float float4v;

typedef __attribute__((address_space(1))) uint32_t g_u32;
typedef __attribute__((address_space(3))) uint32_t l_u32;

// async global->LDS DMA, 16B/lane; LDS dest = wave-uniform base + lane*16
__device__ __forceinline__ void dma16(const void* gsrc, void* ldst) {
  __builtin_amdgcn_global_load_lds((g_u32*)gsrc, (l_u32*)ldst, 16, 0, 0);
}

__device__ __forceinline__ uint32_t rotl32(uint32_t x, int r) {
  return __builtin_rotateleft32(x, (uint32_t)r);
}

// Threefry-2x32, key=(0,42), counter=(0, c); out0^out1 (JAX partitionable).
__device__ __forceinline__ uint32_t threefry_bits(uint32_t c) {
  const uint32_t k0 = 0u, k1 = 42u;
  const uint32_t k2 = 0x1BD11BDAu ^ k0 ^ k1;
  uint32_t x0 = 0u + k0;
  uint32_t x1 = c + k1;
#define TF_R(r) { x0 += x1; x1 = rotl32(x1, r); x1 ^= x0; }
  TF_R(13) TF_R(15) TF_R(26) TF_R(6)
  x0 += k1; x1 += k2 + 1u;
  TF_R(17) TF_R(29) TF_R(16) TF_R(24)
  x0 += k2; x1 += k0 + 2u;
  TF_R(13) TF_R(15) TF_R(26) TF_R(6)
  x0 += k0; x1 += k1 + 3u;
  TF_R(17) TF_R(29) TF_R(16) TF_R(24)
  x0 += k1; x1 += k2 + 4u;
  TF_R(13) TF_R(15) TF_R(26) TF_R(6)
  x0 += k2; x1 += k0 + 5u;
#undef TF_R
  return x0 ^ x1;
}

// accurate gumbel for the v1 fallback path
__device__ __forceinline__ float gumbel_at_v1(uint32_t idx) {
  uint32_t bits = threefry_bits(idx);
  float u = __uint_as_float((bits >> 9) | 0x3f800000u) - 1.0f;
  u = fmaxf(u, 1.17549435e-38f);
  return -logf(-logf(u));
}

__device__ __forceinline__ unsigned short f2bf(float x) {
  uint32_t u = __float_as_uint(x);
  u += 0x7fffu + ((u >> 16) & 1u);
  return (unsigned short)(u >> 16);
}
__device__ __forceinline__ float bf2f(unsigned short h) {
  return __uint_as_float(((uint32_t)h) << 16);
}

// ================= prep: cb fp32 -> bf16 hi + chunk-blocked transpose =================
__global__ __launch_bounds__(256)
void vq_prep(const float* __restrict__ cb, char* __restrict__ ws) {
  __shared__ unsigned short lhs[32 * 260];
  const int c = blockIdx.x;
  const int tid = threadIdx.x;
  const int k0 = c * 32;
  unsigned short* cbhi = (unsigned short*)(ws + WS_CBHI);
  unsigned short* cbt  = (unsigned short*)(ws + WS_CBT);
#pragma unroll
  for (int i = 0; i < 8; ++i) {
    int F = tid + i * 256;
    int code = F >> 6, d4 = (F & 63) * 4;
    float4 v = *(const float4*)(cb + (size_t)(k0 + code) * DIMV + d4);
    unsigned short h0 = f2bf(v.x), h1 = f2bf(v.y), h2 = f2bf(v.z), h3 = f2bf(v.w);
    ushort4 hv = {h0, h1, h2, h3};
    *(ushort4*)(cbhi + (size_t)(k0 + code) * DIMV + d4) = hv;
    *(ushort4*)(&lhs[code * 260 + d4]) = hv;
  }
  __syncthreads();
  const int d = tid;
  unsigned short vals[32];
#pragma unroll
  for (int cc = 0; cc < 32; ++cc) vals[cc] = lhs[cc * 260 + d];
  unsigned short* base = cbt + (size_t)c * 8192 + (size_t)d * 32;
#pragma unroll
  for (int j = 0; j < 8; ++j) {
    ushort4 w = {vals[4 * j], vals[4 * j + 1], vals[4 * j + 2], vals[4 * j + 3]};
    *(ushort4*)(base + j * 4) = w;
  }
}

// ================= main v7: 4 blocks/CU, single CBT buffer, lean phase C =================
__global__ __launch_bounds__(256, 4)
void vq_main_v2(const float* __restrict__ z, const float* __restrict__ cb,
                float* __restrict__ out, char* __restrict__ ws) {
  __shared__ __align__(16) char sm[SMEM_BYTES];
  const int tid  = threadIdx.x;
  const int wave = tid >> 6;
  const int lane = tid & 63;
  const int quad = lane >> 4;
  const int n    = lane & 15;
  const int mt   = wave & 1;
  const int nt   = wave >> 1;
  const int r0   = blockIdx.x * RT;
  const int myrow = mt * 16 + quad * 4;      // C-layout base row
  const char* cbhi_b = ws + WS_CBHI;
  const char* cbt_b  = ws + WS_CBT;
  float* wsA = (float*)(ws + WS_ACC);

  // ---- prologue: stage z fp32 tile (LDS overlay), build A-fragments ----
  {
    float* zts = (float*)sm;
#pragma unroll
    for (int i = 0; i < 8; ++i) {
      int F = tid + i * 256;
      int row = F >> 6, d4 = (F & 63) * 4;
      *(float4*)(zts + row * ZT_ROWF + d4) =
          *(const float4*)(z + (size_t)(r0 + row) * DIMV + d4);
    }
  }
  __syncthreads();
  short8 zhi[8];
  {
    const float* zts = (const float*)sm;
    const int rowl = mt * 16 + n;            // A-frag m = lane&15
#pragma unroll
    for (int ks = 0; ks < 8; ++ks) {
      const float* zp = zts + rowl * ZT_ROWF + ks * 32 + quad * 8;
      float4 f0 = *(const float4*)zp;
      float4 f1 = *(const float4*)(zp + 4);
      zhi[ks][0] = (short)f2bf(f0.x); zhi[ks][1] = (short)f2bf(f0.y);
      zhi[ks][2] = (short)f2bf(f0.z); zhi[ks][3] = (short)f2bf(f0.w);
      zhi[ks][4] = (short)f2bf(f1.x); zhi[ks][5] = (short)f2bf(f1.y);
      zhi[ks][6] = (short)f2bf(f1.z); zhi[ks][7] = (short)f2bf(f1.w);
    }
  }
  __syncthreads();   // all waves done reading z-tile (CB1H/CBT region reuse)

  // ---- prologue staging: CB1H(0) only; CBT(0) issued at S0(0) ----
#pragma unroll
  for (int i = 0; i < 4; ++i) {
    int b = wave * 4 + i;
    dma16(cbhi_b + (size_t)(2 * b) * 512 + (size_t)lane * 16, sm + CB1H_OFF + b * BSTRIDE);
  }

  // ---- per-lane persistent state ----
  float skl[4] = {0.f, 0.f, 0.f, 0.f};
  float tkl[4] = {0.f, 0.f, 0.f, 0.f};
  float s2l[4] = {0.f, 0.f, 0.f, 0.f};
  float v1[4], v2[4];
  int   i1[4], i2[4];
  uint32_t idxr[4];
#pragma unroll
  for (int r = 0; r < 4; ++r) {
    v1[r] = -INFINITY; v2[r] = -INFINITY;
    i1[r] = 0x7fffffff; i2[r] = 0x7fffffff;
    idxr[r] = (uint32_t)(r0 + myrow + r) * (uint32_t)N_CODES + (uint32_t)(nt * 16 + n);
  }
  float4v acc2[8];
#pragma unroll
  for (int t = 0; t < 8; ++t) acc2[t] = (float4v){0.f, 0.f, 0.f, 0.f};

  const int kc = nt * 16 + n;
  const char* bbase = sm + CB1H_OFF + (kc >> 1) * BSTRIDE + (kc & 1) * 512 + quad * 16;

  for (int c = 0; c < NCHUNK; ++c) {
    __syncthreads();   // S0: drains CB1H(c) DMA (behind GEMM2(c-1))

    // stage CBT(c); drains at S4(c) behind GEMM1+phaseC (fully hidden)
#pragma unroll
    for (int i = 0; i < 4; ++i) {
      int b = wave * 4 + i;
      dma16(cbt_b + (size_t)c * 16384 + (size_t)b * 1024 + (size_t)lane * 16,
            sm + CBT_OFF + b * BSTRIDE);
    }

    // ---- GEMM1: logits, hh term only, 2 independent chains ----
    float4v e0 = (float4v){0.f, 0.f, 0.f, 0.f};
    float4v e1 = (float4v){0.f, 0.f, 0.f, 0.f};
#pragma unroll
    for (int ks = 0; ks < 4; ++ks) {
      short8 ba = *(const short8*)(bbase + (2 * ks) * 64);
      short8 bb = *(const short8*)(bbase + (2 * ks + 1) * 64);
      e0 = __builtin_amdgcn_mfma_f32_16x16x32_bf16(zhi[2 * ks], ba, e0, 0, 0, 0);
      e1 = __builtin_amdgcn_mfma_f32_16x16x32_bf16(zhi[2 * ks + 1], bb, e1, 0, 0, 0);
    }
    float4v acc1 = e0 + e1;

    // ---- phase C: threefry, KL stats, top2, P-hi write ----
    const int codeg0 = c * CK + kc;
#pragma unroll
    for (int r = 0; r < 4; ++r) {
      float l = acc1[r];
      uint32_t bits = threefry_bits(idxr[r]);
      idxr[r] += 32u;
      float u = __uint_as_float((bits >> 9) | 0x3f800000u) - 1.0f;   // [0,1)
      // t = -ln(u); winner-element rel. error self-cancels in softmax ratio
      float t = -0.69314718056f * __log2f(fmaxf(u, 1.17549435e-38f));
      t = fmaxf(t, 1.0e-10f);              // guard t->0 => inf p
      float e = __expf(l);
      skl[r] += e;
      tkl[r] = fmaf(e, l, tkl[r]);
      bool b1 = l > v1[r];
      bool b2 = l > v2[r];
      v2[r] = b1 ? v1[r] : (b2 ? l : v2[r]);
      i2[r] = b1 ? i1[r] : (b2 ? codeg0 : i2[r]);
      v1[r] = b1 ? l : v1[r];
      i1[r] = b1 ? codeg0 : i1[r];
      // exp(l + g - 12) == exp(l)/t * e^-12 ; P stored hi-only bf16
      float p = e * __builtin_amdgcn_rcpf(t) * 6.1442123533282097e-06f;
      unsigned short ph = f2bf(p);
      s2l[r] += bf2f(ph);                  // denominator from rounded P
      *(unsigned short*)(sm + P_OFF + (myrow + r) * P_ROW + kc * 2) = ph;
    }
    __syncthreads();   // S4: P ready; CBT(c) drained (hidden)

    // stage CB1H(c+1); drains at S0(c+1) behind GEMM2
    if (c + 1 < NCHUNK) {
      const size_t k1 = (size_t)(c + 1) * CK;
#pragma unroll
      for (int i = 0; i < 4; ++i) {
        int b = wave * 4 + i;
        dma16(cbhi_b + (k1 + 2 * b) * 512 + (size_t)lane * 16, sm + CB1H_OFF + b * BSTRIDE);
      }
    }

    // ---- GEMM2: z_q += P_hi * CBT ----
    {
      short8 pah0 = *(const short8*)(sm + P_OFF + n * P_ROW + quad * 16);
      short8 pah1 = *(const short8*)(sm + P_OFF + (16 + n) * P_ROW + quad * 16);
#pragma unroll
      for (int t = 0; t < 4; ++t) {
        int dt = wave * 4 + t;               // dims dt*16 .. dt*16+15
        short8 bb = *(const short8*)(sm + CBT_OFF + dt * BSTRIDE + n * 64 + quad * 16);
        acc2[t * 2 + 0] = __builtin_amdgcn_mfma_f32_16x16x32_bf16(pah0, bb, acc2[t * 2 + 0], 0, 0, 0);
        acc2[t * 2 + 1] = __builtin_amdgcn_mfma_f32_16x16x32_bf16(pah1, bb, acc2[t * 2 + 1], 0, 0, 0);
      }
    }
  }

  // ================= epilogue =================
  // reduce scalar stats over the 16-lane n-group (registers only)
#pragma unroll
  for (int m = 1; m <= 8; m <<= 1) {
#pragma unroll
    for (int r = 0; r < 4; ++r) {
      s2l[r] += __shfl_xor(s2l[r], m);
      skl[r] += __shfl_xor(skl[r], m);
      tkl[r] += __shfl_xor(tkl[r], m);
    }
  }
  if (n == 0) {
    int off = (nt * 32 + myrow) * 4;
    float4 fs = {s2l[0], s2l[1], s2l[2], s2l[3]};
    *(float4*)(sm + S2B_OFF + off) = fs;
    float4 fk = {skl[0], skl[1], skl[2], skl[3]};
    *(float4*)(sm + SKL_OFF + off) = fk;
    float4 ft = {tkl[0], tkl[1], tkl[2], tkl[3]};
    *(float4*)(sm + TKL_OFF + off) = ft;
  }
  // dump per-lane top-2 candidates over CB1H region (last read pre-S4(255)):
  // cand[row][nt*32 + n*2 + rank] = (v, idx)
#pragma unroll
  for (int r = 0; r < 4; ++r) {
    char* cbase = sm + CAND_OFF + (myrow + r) * 512 + (nt * 32 + n * 2) * 8;
    *(float*)(cbase + 0) = v1[r];
    *(int*)(cbase + 4)   = i1[r];
    *(float*)(cbase + 8) = v2[r];
    *(int*)(cbase + 12)  = i2[r];
  }
  __syncthreads();                           // E1

  // KL per row (one lane per row)
  if (tid < 32) {
    int r = tid;
    const float* sklb = (const float*)(sm + SKL_OFF);
    const float* tklb = (const float*)(sm + TKL_OFF);
    float S = sklb[r] + sklb[32 + r];
    float T = tklb[r] + tklb[32 + r];
    float klr = T / S - __logf(S) + 9.010913347279288f;   // ln(8192)
#pragma unroll
    for (int m = 1; m <= 16; m <<= 1) klr += __shfl_xor(klr, m);
    if (r == 0) atomicAdd(&wsA[0], klr);
  }

  // codes: top-8 by noisy logit, fp64 refine vs global z/cb; 2 lanes per row
  if (tid < 64) {
    int r = tid >> 1, h = tid & 1;
    const char* cbase = sm + CAND_OFF + r * 512 + h * 256;   // 32 entries x 8B
    float bv[8]; int bi8[8];
#pragma unroll
    for (int k = 0; k < 8; ++k) { bv[k] = -INFINITY; bi8[k] = 0x7fffffff; }
    for (int s = 0; s < 32; ++s) {
      float v = *(const float*)(cbase + s * 8);
      int  id = *(const int*)(cbase + s * 8 + 4);
      if ((v > bv[7]) || (v == bv[7] && id < bi8[7])) {
        float cv = v; int ci = id;
#pragma unroll
        for (int k = 0; k < 8; ++k) {
          bool sw = (cv > bv[k]) || (cv == bv[k] && ci < bi8[k]);
          float tv = bv[k]; int ti = bi8[k];
          if (sw) { bv[k] = cv; bi8[k] = ci; cv = tv; ci = ti; }
        }
      }
    }
    // merge partner half's top-8
    float ovv[8]; int ovi[8];
#pragma unroll
    for (int k = 0; k < 8; ++k) {
      ovv[k] = __shfl_xor(bv[k], 1);
      ovi[k] = __shfl_xor(bi8[k], 1);
    }
#pragma unroll
    for (int kk = 0; kk < 8; ++kk) {
      float cv = ovv[kk]; int ci = ovi[kk];
      if ((cv > bv[7]) || (cv == bv[7] && ci < bi8[7])) {
#pragma unroll
        for (int k = 0; k < 8; ++k) {
          bool sw = (cv > bv[k]) || (cv == bv[k] && ci < bi8[k]);
          float tv = bv[k]; int ti = bi8[k];
          if (sw) { bv[k] = cv; bi8[k] = ci; cv = tv; ci = ti; }
        }
      }
    }
    // fp64 refine 4 candidates per lane (lane h takes entries h*4..h*4+3)
    const float* zp = z + (size_t)(r0 + r) * DIMV;
    double best = -1.0e300;
    int bidx = 0x7fffffff;
#pragma unroll
    for (int k = 0; k < 4; ++k) {
      int cidx = bi8[h * 4 + k];
      const float* cp = cb + (size_t)cidx * DIMV;
      double d = 0.0;
      for (int dd = 0; dd < DIMV; dd += 4) {
        float4 zv = *(const float4*)(zp + dd);
        float4 xv = *(const float4*)(cp + dd);
        d += (double)zv.x * xv.x + (double)zv.y * xv.y +
             (double)zv.z * xv.z + (double)zv.w * xv.w;
      }
      if (d > best || (d == best && cidx < bidx)) { best = d; bidx = cidx; }
    }
    double obest = __shfl_xor(best, 1);
    int    obidx = __shfl_xor(bidx, 1);
    bool take = (obest > best) || (obest == best && obidx < bidx);
    int finali = take ? obidx : bidx;
    if (h == 0) out[OUT_CODE + (size_t)(r0 + r)] = (float)finali;
  }

  // z_q_st + commit partial (z read from global; L2-hot)
  float invm0[4], invm1[4];
  {
    const float* s2b = (const float*)(sm + S2B_OFF);
#pragma unroll
    for (int e = 0; e < 4; ++e) {
      float Sa = s2b[quad * 4 + e] + s2b[32 + quad * 4 + e];
      float Sb = s2b[16 + quad * 4 + e] + s2b[32 + 16 + quad * 4 + e];
      invm0[e] = 1.0f / Sa;
      invm1[e] = 1.0f / Sb;
    }
  }
  float cpart = 0.f;
#pragma unroll
  for (int t = 0; t < 4; ++t) {
    int dim = (wave * 4 + t) * 16 + n;
#pragma unroll
    for (int ms = 0; ms < 2; ++ms) {
      float4v a = acc2[t * 2 + ms];
#pragma unroll
      for (int e = 0; e < 4; ++e) {
        int row = ms * 16 + quad * 4 + e;
        float q = a[e] * (ms ? invm1[e] : invm0[e]);
        float zv = z[(size_t)(r0 + row) * DIMV + dim];
        float err = q - zv;
        cpart += err * err;
        out[(size_t)(r0 + row) * DIMV + dim] = zv + err;
      }
    }
  }
#pragma unroll
  for (int m = 1; m <= 32; m <<= 1) cpart += __shfl_xor(cpart, m);
  if (lane == 0) atomicAdd(&wsA[1], cpart);
}

// ================= fallback v1 (fp32 VALU, needs only 8B ws) =================
#define ZSTRIDE  260
#define CSTRIDE  260
#define PSTRIDE  36
#define RSTRIDE  17

__global__ __launch_bounds__(256, 2)
void vq_main_v1(const float* __restrict__ z, const float* __restrict__ cb,
                float* __restrict__ out, float* __restrict__ ws_acc) {
  __shared__ float zt[RT * ZSTRIDE];
  __shared__ float cbt[CK * CSTRIDE];
  __shared__ float ptile[RT * PSTRIDE];
  __shared__ float redb[RT * RSTRIDE];
  __shared__ float m2s[RT], s2s[RT], scls[RT];

  const int tid = threadIdx.x;
  const int r0  = blockIdx.x * RT;
#pragma unroll
  for (int p = 0; p < 8; ++p) {
    int q = tid + p * 256;
    int i = q >> 6, c4 = (q & 63) * 4;
    *(float4*)(&zt[i * ZSTRIDE + c4]) = *(const float4*)(z + (size_t)(r0 + i) * DIMV + c4);
  }
  if (tid < RT) { m2s[tid] = -INFINITY; s2s[tid] = 0.f; scls[tid] = 0.f; }
  const int tr = tid & 15, tk = tid >> 4, rowg = tid >> 6;
  const int d4 = (tid & 63) * 4;
  float c_m[2][2], c_s[2][2], c_t[2][2];
  int   c_i[2][2];
#pragma unroll
  for (int a = 0; a < 2; ++a)
#pragma unroll
    for (int b = 0; b < 2; ++b) { c_m[a][b] = -INFINITY; c_s[a][b] = 0.f; c_t[a][b] = 0.f; c_i[a][b] = 0; }
  float acc2[8][4];
#pragma unroll
  for (int j = 0; j < 8; ++j)
#pragma unroll
    for (int e = 0; e < 4; ++e) acc2[j][e] = 0.f;
  __syncthreads();
  for (int c = 0; c < NCHUNK; ++c) {
    const int k0 = c * CK;
#pragma unroll
    for (int p = 0; p < 8; ++p) {
      int q = tid + p * 256;
      int i = q >> 6, c4 = (q & 63) * 4;
      *(float4*)(&cbt[i * CSTRIDE + c4]) = *(const float4*)(cb + (size_t)(k0 + i) * DIMV + c4);
    }
    __syncthreads();
    float l00 = 0.f, l01 = 0.f, l10 = 0.f, l11 = 0.f;
    {
      const float* zp0 = &zt[tr * ZSTRIDE];
      const float* zp1 = &zt[(tr + 16) * ZSTRIDE];
      const float* bp0 = &cbt[tk * CSTRIDE];
      const float* bp1 = &cbt[(tk + 16) * CSTRIDE];
#pragma unroll 4
      for (int d = 0; d < DIMV; d += 4) {
        float4 a0 = *(const float4*)(zp0 + d);
        float4 a1 = *(const float4*)(zp1 + d);
        float4 b0 = *(const float4*)(bp0 + d);
        float4 b1 = *(const float4*)(bp1 + d);
        l00 += a0.x*b0.x + a0.y*b0.y + a0.z*b0.z + a0.w*b0.w;
        l01 += a0.x*b1.x + a0.y*b1.y + a0.z*b1.z + a0.w*b1.w;
        l10 += a1.x*b0.x + a1.y*b0.y + a1.z*b0.z + a1.w*b0.w;
        l11 += a1.x*b1.x + a1.y*b1.y + a1.z*b1.z + a1.w*b1.w;
      }
    }
    float lv2[2][2] = {{l00, l01}, {l10, l11}};
    float a2[2][2];
#pragma unroll
    for (int a = 0; a < 2; ++a) {
      int grow = r0 + tr + a * 16;
#pragma unroll
      for (int b = 0; b < 2; ++b) {
        int gk = k0 + tk + b * 16;
        float g  = gumbel_at_v1((uint32_t)grow * (uint32_t)N_CODES + (uint32_t)gk);
        float lv = lv2[a][b];
        a2[a][b] = lv + g;
        if (lv > c_m[a][b]) {
          float sc = expf(c_m[a][b] - lv);
          c_s[a][b] = c_s[a][b] * sc + 1.0f;
          c_t[a][b] = c_t[a][b] * sc + lv;
          c_m[a][b] = lv;
          c_i[a][b] = gk;
        } else {
          float e = expf(lv - c_m[a][b]);
          c_s[a][b] += e;
          c_t[a][b] += e * lv;
        }
      }
    }
    redb[tr * RSTRIDE + tk]        = fmaxf(a2[0][0], a2[0][1]);
    redb[(tr + 16) * RSTRIDE + tk] = fmaxf(a2[1][0], a2[1][1]);
    __syncthreads();
    if (tid < RT) {
      float cm = -INFINITY;
#pragma unroll
      for (int j = 0; j < 16; ++j) cm = fmaxf(cm, redb[tid * RSTRIDE + j]);
      float m2n = fmaxf(m2s[tid], cm);
      scls[tid] = expf(m2s[tid] - m2n);
      m2s[tid]  = m2n;
    }
    __syncthreads();
#pragma unroll
    for (int a = 0; a < 2; ++a) {
      int row = tr + a * 16;
      float m2r = m2s[row];
      float p0 = expf(a2[a][0] - m2r);
      float p1 = expf(a2[a][1] - m2r);
      ptile[row * PSTRIDE + tk]      = p0;
      ptile[row * PSTRIDE + tk + 16] = p1;
      redb[row * RSTRIDE + tk] = p0 + p1;
    }
    __syncthreads();
    if (tid < RT) {
      float ss = 0.f;
#pragma unroll
      for (int j = 0; j < 16; ++j) ss += redb[tid * RSTRIDE + j];
      s2s[tid] = s2s[tid] * scls[tid] + ss;
    }
#pragma unroll
    for (int j = 0; j < 8; ++j) {
      float sc = scls[rowg * 8 + j];
      acc2[j][0] *= sc; acc2[j][1] *= sc; acc2[j][2] *= sc; acc2[j][3] *= sc;
    }
    for (int k4 = 0; k4 < CK; k4 += 4) {
      float4 cb0 = *(const float4*)(&cbt[(k4 + 0) * CSTRIDE + d4]);
      float4 cb1v = *(const float4*)(&cbt[(k4 + 1) * CSTRIDE + d4]);
      float4 cb2 = *(const float4*)(&cbt[(k4 + 2) * CSTRIDE + d4]);
      float4 cb3 = *(const float4*)(&cbt[(k4 + 3) * CSTRIDE + d4]);
#pragma unroll
      for (int j = 0; j < 8; ++j) {
        float4 p4 = *(const float4*)(&ptile[(rowg * 8 + j) * PSTRIDE + k4]);
        acc2[j][0] += p4.x*cb0.x + p4.y*cb1v.x + p4.z*cb2.x + p4.w*cb3.x;
        acc2[j][1] += p4.x*cb0.y + p4.y*cb1v.y + p4.z*cb2.y + p4.w*cb3.y;
        acc2[j][2] += p4.x*cb0.z + p4.y*cb1v.z + p4.z*cb2.z + p4.w*cb3.z;
        acc2[j][3] += p4.x*cb0.w + p4.y*cb1v.w + p4.z*cb2.w + p4.w*cb3.w;
      }
    }
    __syncthreads();
  }
  float* kbuf = cbt;
#pragma unroll
  for (int a = 0; a < 2; ++a) {
    float m0 = c_m[a][0], m1v = c_m[a][1];
    float m, s, t; int bi;
    if (m0 >= m1v) {
      float e = expf(m1v - m0);
      m = m0; s = c_s[a][0] + c_s[a][1] * e; t = c_t[a][0] + c_t[a][1] * e;
    } else {
      float e = expf(m0 - m1v);
      m = m1v; s = c_s[a][0] * e + c_s[a][1]; t = c_t[a][0] * e + c_t[a][1];
    }
    if (m0 > m1v)      bi = c_i[a][0];
    else if (m1v > m0) bi = c_i[a][1];
    else               bi = min(c_i[a][0], c_i[a][1]);
    int row = tr + a * 16;
    kbuf[row * 65 + tk * 4 + 0] = m;
    kbuf[row * 65 + tk * 4 + 1] = s;
    kbuf[row * 65 + tk * 4 + 2] = t;
    kbuf[row * 65 + tk * 4 + 3] = (float)bi;
  }
  __syncthreads();
  if (tid < RT) {
    int r = tid;
    float M = -INFINITY, S = 0.f, T = 0.f, BM = -INFINITY;
    int BI = 0x7fffffff;
    for (int j = 0; j < 16; ++j) {
      float m  = kbuf[r * 65 + j * 4 + 0];
      float s  = kbuf[r * 65 + j * 4 + 1];
      float t  = kbuf[r * 65 + j * 4 + 2];
      int   bi = (int)kbuf[r * 65 + j * 4 + 3];
      if (m <= M) {
        float e = expf(m - M);
        S += s * e; T += t * e;
      } else {
        float e = expf(M - m);
        S = S * e + s; T = T * e + t; M = m;
      }
      if (m > BM || (m == BM && bi < BI)) { BM = m; BI = bi; }
    }
    float kl = logf((float)N_CODES) + T / S - M - logf(S);
    atomicAdd(&ws_acc[0], kl);
    out[OUT_CODE + (size_t)(r0 + r)] = (float)BI;
  }
  float cpart = 0.f;
#pragma unroll
  for (int j = 0; j < 8; ++j) {
    int row  = rowg * 8 + j;
    int grow = r0 + row;
    float inv = 1.0f / s2s[row];
    float4 zv = *(const float4*)(&zt[row * ZSTRIDE + d4]);
    float q0 = acc2[j][0] * inv, q1 = acc2[j][1] * inv;
    float q2 = acc2[j][2] * inv, q3 = acc2[j][3] * inv;
    float e0 = q0 - zv.x, e1 = q1 - zv.y, e2 = q2 - zv.z, e3 = q3 - zv.w;
    cpart += e0*e0 + e1*e1 + e2*e2 + e3*e3;
    float4 o;
    o.x = zv.x + e0; o.y = zv.y + e1; o.z = zv.z + e2; o.w = zv.w + e3;
    *(float4*)(&out[(size_t)grow * DIMV + d4]) = o;
  }
#pragma unroll
  for (int off = 32; off > 0; off >>= 1) cpart += __shfl_down(cpart, off, 64);
  __syncthreads();
  if ((tid & 63) == 0) redb[tid >> 6] = cpart;
  __syncthreads();
  if (tid == 0) {
    float cs = redb[0] + redb[1] + redb[2] + redb[3];
    atomicAdd(&ws_acc[1], cs);
  }
}

__global__ void vq_finalize(const float* __restrict__ ws_acc, float* __restrict__ out) {
  if (threadIdx.x == 0 && blockIdx.x == 0) {
    float kl = 0.01f * (ws_acc[0] / (float)N_ROWS);
    float cm = 0.25f * (ws_acc[1] / (float)OUT_ZQ_N);
    out[OUT_LOSS] = cm + kl;
  }
}

extern "C" void kernel_launch(void* const* d_in, const int* in_sizes, int n_in,
                              void* d_out, int out_size, void* d_ws, size_t ws_size,
                              hipStream_t stream) {
  (void)in_sizes; (void)n_in; (void)out_size;
  const float* z  = (const float*)d_in[0];
  const float* cb = (const float*)d_in[1];
  float* out = (float*)d_out;
  if (ws_size >= (size_t)WS_NEED) {
    char* ws = (char*)d_ws;
    hipMemsetAsync(ws + WS_ACC, 0, 8, stream);
    vq_prep<<<256, 256, 0, stream>>>(cb, ws);
    vq_main_v2<<<N_ROWS / RT, 256, 0, stream>>>(z, cb, out, ws);
    vq_finalize<<<1, 64, 0, stream>>>((const float*)(ws + WS_ACC), out);
  } else {
    float* ws = (float*)d_ws;
    hipMemsetAsync(ws, 0, 8, stream);
    vq_main_v1<<<N_ROWS / RT, 256, 0, stream>>>(z, cb, out, ws);
    vq_finalize<<<1, 64, 0, stream>>>(ws, out);
  }
}